// Round 14
// baseline (317.185 us; speedup 1.0000x reference)
//
#include <hip/hip_runtime.h>
#include <hip/hip_bf16.h>
#include <stdint.h>

#define Bz 2
#define Sz 2048
#define Dz 768
#define Hz 12
#define DHz 64
#define Mz (Bz*Sz)    // 4096
#define NQT16 128     // 16-row q-tiles per (b,h)

typedef __attribute__((ext_vector_type(4))) float f32x4;
typedef __attribute__((ext_vector_type(8))) short bf16x8;
typedef unsigned short u16;
typedef __attribute__((ext_vector_type(8))) unsigned short u16x8;

__device__ __forceinline__ u16 f2bf(float f) {
  union { float f; uint32_t u; } c; c.f = f;
  uint32_t u = c.u;
  return (u16)((u + 0x7fffu + ((u >> 16) & 1u)) >> 16);
}

#define GLL16(gsrc, ldst) \
  __builtin_amdgcn_global_load_lds((const __attribute__((address_space(1))) void*)(gsrc), \
                                   (__attribute__((address_space(3))) void*)(ldst), 16, 0, 0)

__device__ __forceinline__ f32x4 mfma16(bf16x8 a, bf16x8 b, f32x4 c) {
  return __builtin_amdgcn_mfma_f32_16x16x32_bf16(a, b, c, 0, 0, 0);
}

// ---------------- pre-pass: fp32 -> bf16 (q,k,v fused in one launch) ----------------
__global__ void cvt3_kernel(const float* __restrict__ qa, const float* __restrict__ ka,
                            const float* __restrict__ va,
                            u16* __restrict__ qo, u16* __restrict__ ko, u16* __restrict__ vo,
                            int n8) {
  int i = blockIdx.x * blockDim.x + threadIdx.x;
  if (i >= n8) return;
  int z = blockIdx.y;
  const float* src = (z == 0) ? qa : (z == 1) ? ka : va;
  u16* dst = (z == 0) ? qo : (z == 1) ? ko : vo;
  const float4* s4 = (const float4*)src;
  float4 a = s4[(size_t)i * 2];
  float4 b = s4[(size_t)i * 2 + 1];
  u16x8 o;
  o[0] = f2bf(a.x); o[1] = f2bf(a.y); o[2] = f2bf(a.z); o[3] = f2bf(a.w);
  o[4] = f2bf(b.x); o[5] = f2bf(b.y); o[6] = f2bf(b.z); o[7] = f2bf(b.w);
  *(u16x8*)(dst + (size_t)i * 8) = o;
}

// ---------------- pre-pass: W [K][N] fp32 -> Wt [N][K] bf16 (4 weights fused) ----------------
__global__ void wtrans4_kernel(const float* __restrict__ W0, const float* __restrict__ W1,
                               const float* __restrict__ W2, const float* __restrict__ W3,
                               u16* __restrict__ T0, u16* __restrict__ T1,
                               u16* __restrict__ T2, u16* __restrict__ T3) {
  __shared__ float tile[32][33];
  int z = blockIdx.z;
  const float* W = (z == 0) ? W0 : (z == 1) ? W1 : (z == 2) ? W2 : W3;
  u16* Wt = (z == 0) ? T0 : (z == 1) ? T1 : (z == 2) ? T2 : T3;
  int bx = blockIdx.x * 32, by = blockIdx.y * 32;
  int tx = threadIdx.x & 31, ty = threadIdx.x >> 5;   // 256 threads: ty 0..7
#pragma unroll
  for (int i = 0; i < 32; i += 8)
    tile[ty + i][tx] = W[(size_t)(by + ty + i) * Dz + bx + tx];
  __syncthreads();
#pragma unroll
  for (int i = 0; i < 32; i += 8)
    Wt[(size_t)(bx + ty + i) * Dz + by + tx] = f2bf(tile[tx][ty + i]);
}

// ---------------- GEMM core (R10/R13, proven): 128x128, triple-buffer, 1 barrier, counted vmcnt
// mode 0: Q -> fragment layout Qf[bh][qt=s>>4][kk=dh>>5][lane][e]         (scaled by oscale)
// mode 3: K -> fragment layout Kf[bh][kt=s>>6][j=(s>>4)&3][kk=dh>>5][lane][e]
// mode 1: V -> fragment layout Vf[bh][kt=s>>6][fo=dh>>4][kk=(s>>5)&1][lane][e]
// mode 2: fp32 out [M][N] (output projection)
__device__ __forceinline__ void gemm_core(
    const u16* __restrict__ A, const u16* __restrict__ Wt,
    const float* __restrict__ bias, void* __restrict__ out, int mode, float oscale,
    u16 (*As)[128 * 32], u16 (*Bs)[128 * 32])
{
  const int tid = threadIdx.x;
  const int wid = tid >> 6, lane = tid & 63;
  const int wm = wid >> 1, wn = wid & 1;
  const int m0 = blockIdx.x * 128, n0 = blockIdx.y * 128;
  const int fq = lane >> 4, fr = lane & 15;

  int aoff[2];
#pragma unroll
  for (int c = 0; c < 2; ++c) {
    int off  = (wid * 2 + c) * 1024 + lane * 16;
    int row  = off >> 6;
    int colb = (off & 63) ^ (((row >> 1) & 3) << 4);
    aoff[c]  = row * Dz + (colb >> 1);
  }

  int raddr[4], rbaddr[4];
#pragma unroll
  for (int f = 0; f < 4; ++f) {
    int rowA = wm * 64 + f * 16 + fr;
    raddr[f]  = rowA * 64 + ((fq * 16) ^ (((rowA >> 1) & 3) << 4));
    int rowB = wn * 64 + f * 16 + fr;
    rbaddr[f] = rowB * 64 + ((fq * 16) ^ (((rowB >> 1) & 3) << 4));
  }

  f32x4 acc[4][4];
  const f32x4 zero = {0.f, 0.f, 0.f, 0.f};
#pragma unroll
  for (int i = 0; i < 4; ++i)
#pragma unroll
    for (int j = 0; j < 4; ++j) acc[i][j] = zero;

  const u16* Abase = A + (size_t)m0 * Dz;
  const u16* Bbase = Wt + (size_t)n0 * Dz;

  const int NKT = Dz / 32;   // 24
#pragma unroll
  for (int c = 0; c < 2; ++c) {
    GLL16(Abase + aoff[c], (char*)As[0] + (wid * 2 + c) * 1024);
    GLL16(Bbase + aoff[c], (char*)Bs[0] + (wid * 2 + c) * 1024);
  }
  int cur = 0;

  for (int kt = 0; kt < NKT; ++kt) {
    int nx = cur + 1; if (nx == 3) nx = 0;
    if (kt + 1 < NKT) {
      int ke = (kt + 1) * 32;
#pragma unroll
      for (int c = 0; c < 2; ++c) {
        GLL16(Abase + ke + aoff[c], (char*)As[nx] + (wid * 2 + c) * 1024);
        GLL16(Bbase + ke + aoff[c], (char*)Bs[nx] + (wid * 2 + c) * 1024);
      }
      asm volatile("s_waitcnt vmcnt(4)" ::: "memory");
    } else {
      asm volatile("s_waitcnt vmcnt(0)" ::: "memory");
    }
    __builtin_amdgcn_s_barrier();
    __builtin_amdgcn_sched_barrier(0);

    bf16x8 af[4], bf[4];
#pragma unroll
    for (int f = 0; f < 4; ++f) {
      af[f] = *(const bf16x8*)((const char*)As[cur] + raddr[f]);
      bf[f] = *(const bf16x8*)((const char*)Bs[cur] + rbaddr[f]);
    }
    __builtin_amdgcn_s_setprio(1);
#pragma unroll
    for (int i = 0; i < 4; ++i)
#pragma unroll
      for (int j = 0; j < 4; ++j)
        acc[i][j] = mfma16(af[i], bf[j], acc[i][j]);
    __builtin_amdgcn_s_setprio(0);
    cur = nx;
  }

  if (mode == 2) {
    float* O = (float*)out;
#pragma unroll
    for (int i = 0; i < 4; ++i) {
      int grow = m0 + wm * 64 + i * 16 + fq * 4;
#pragma unroll
      for (int j = 0; j < 4; ++j) {
        int gcol = n0 + wn * 64 + j * 16 + fr;
        float bv = bias[gcol];
#pragma unroll
        for (int r = 0; r < 4; ++r)
          O[(size_t)(grow + r) * Dz + gcol] = acc[i][j][r] + bv;
      }
    }
  } else {
    u16* O = (u16*)out;
#pragma unroll
    for (int i = 0; i < 4; ++i) {
      int grow = m0 + wm * 64 + i * 16 + fq * 4;
#pragma unroll
      for (int j = 0; j < 4; ++j) {
        int gcol = n0 + wn * 64 + j * 16 + fr;
        float bv = bias[gcol];
        int h = gcol >> 6, dh = gcol & 63;
#pragma unroll
        for (int r = 0; r < 4; ++r) {
          int t = grow + r;
          int b = t >> 11, s = t & 2047;
          int bh = b * Hz + h;
          u16 val = f2bf((acc[i][j][r] + bv) * oscale);
          size_t idx;
          if (mode == 0) {        // Q frags
            idx = ((((size_t)bh * 128 + (s >> 4)) * 2 + (dh >> 5)) * 64
                   + ((dh >> 3) & 3) * 16 + (s & 15)) * 8 + (dh & 7);
          } else if (mode == 3) { // K frags
            idx = (((((size_t)bh * 32 + (s >> 6)) * 4 + ((s >> 4) & 3)) * 2 + (dh >> 5)) * 64
                   + ((dh >> 3) & 3) * 16 + (s & 15)) * 8 + (dh & 7);
          } else {                // mode 1: V frags
            idx = (((((size_t)bh * 32 + (s >> 6)) * 4 + (dh >> 4)) * 2 + ((s >> 5) & 1)) * 64
                   + ((s >> 3) & 3) * 16 + (dh & 15)) * 8 + (s & 7);
          }
          O[idx] = val;
        }
      }
    }
  }
}

// Q is pre-scaled by 1/sqrt(DH) * log2(e) so attention can use raw v_exp_f32 (exp2)
#define QSCALE 0.1803368801111404f   // 0.125 * 1.4426950408889634

__global__ __launch_bounds__(256, 2) void gemm_qkv(
    const u16* __restrict__ qb, const u16* __restrict__ kb, const u16* __restrict__ vb,
    const u16* __restrict__ Wqt, const u16* __restrict__ Wkt, const u16* __restrict__ Wvt,
    const float* __restrict__ bq, const float* __restrict__ bk, const float* __restrict__ bv,
    u16* __restrict__ Qf, u16* __restrict__ Kf, u16* __restrict__ Vf)
{
  __shared__ u16 As[3][128 * 32];
  __shared__ u16 Bs[3][128 * 32];
  const u16* A; const u16* W; const float* bias; u16* out; int mode; float osc;
  if (blockIdx.z == 0)      { A = qb; W = Wqt; bias = bq; out = Qf; mode = 0; osc = QSCALE; }
  else if (blockIdx.z == 1) { A = kb; W = Wkt; bias = bk; out = Kf; mode = 3; osc = 1.f; }
  else                      { A = vb; W = Wvt; bias = bv; out = Vf; mode = 1; osc = 1.f; }
  gemm_core(A, W, bias, out, mode, osc, As, Bs);
}

__global__ __launch_bounds__(256, 2) void gemm_out_k(
    const u16* __restrict__ ctx, const u16* __restrict__ Wot,
    const float* __restrict__ bo, float* __restrict__ out)
{
  __shared__ u16 As[3][128 * 32];
  __shared__ u16 Bs[3][128 * 32];
  gemm_core(ctx, Wot, bo, (void*)out, 2, 1.f, As, Bs);
}

// ---------------- flash attention, causal, 1-WAVE 16-ROW Q-TILES, barrier-free ----------------
// grid (NQT16, B*H) = (128, 24) = 3072 one-wave blocks (3 waves/SIMD).
// qt = 127 - blockIdx.x (heavy-first LPT; ~12 blocks/CU smooth the triangular tail).
// K/V/Q pre-formatted in MFMA-fragment order: every fragment load is one coalesced
// 1KB global_load_dwordx4 per wave (L2-hit). No barriers; K prefetched one tile
// ahead in registers; V issued early. Only P round-trips through 2KB LDS.
__global__ __launch_bounds__(64, 4) void attn_kernel(
    const u16* __restrict__ Qf, const u16* __restrict__ Kf,
    const u16* __restrict__ Vf, u16* __restrict__ ctx)
{
  __shared__ u16 Ps[16 * 64];    // 2 KB per-wave P tile
  const int lane = threadIdx.x;
  const int fq = lane >> 4, fr = lane & 15;
  const int qt = (NQT16 - 1) - blockIdx.x;   // 16-row q-tile, heavy first
  const int bh = blockIdx.y;
  const int b = bh / Hz, h = bh % Hz;
  const int qbase = qt * 16;
  const int nkt = (qbase + 79) >> 6;         // k-tiles covering keys <= qbase+15

  const bf16x8* Qf8 = (const bf16x8*)Qf + (size_t)bh * 128 * 2 * 64;
  const bf16x8* Kf8 = (const bf16x8*)Kf + (size_t)bh * 32 * 8 * 64;
  const bf16x8* Vf8 = (const bf16x8*)Vf + (size_t)bh * 32 * 8 * 64;

  bf16x8 aq[2];
#pragma unroll
  for (int kk = 0; kk < 2; ++kk)
    aq[kk] = Qf8[((size_t)qt * 2 + kk) * 64 + lane];

  const f32x4 zero = {0.f, 0.f, 0.f, 0.f};
  f32x4 o[4];
#pragma unroll
  for (int i = 0; i < 4; ++i) o[i] = zero;
  float m_r[4], l_r[4];
#pragma unroll
  for (int r = 0; r < 4; ++r) { m_r[r] = -1e30f; l_r[r] = 0.f; }

  char* Pw = (char*)Ps;

  // preload K fragments for tile 0
  bf16x8 kfr[4][2], knx[4][2], vfr[4][2];
#pragma unroll
  for (int j = 0; j < 4; ++j)
#pragma unroll
    for (int kk = 0; kk < 2; ++kk)
      kfr[j][kk] = Kf8[(size_t)(j * 2 + kk) * 64 + lane];

  for (int kt = 0; kt < nkt; ++kt) {
    // issue V loads for kt (consumed after softmax), then K for kt+1
#pragma unroll
    for (int fo = 0; fo < 4; ++fo)
#pragma unroll
      for (int kk = 0; kk < 2; ++kk)
        vfr[fo][kk] = Vf8[((size_t)kt * 8 + fo * 2 + kk) * 64 + lane];
    if (kt + 1 < nkt) {
#pragma unroll
      for (int j = 0; j < 4; ++j)
#pragma unroll
        for (int kk = 0; kk < 2; ++kk)
          knx[j][kk] = Kf8[((size_t)(kt + 1) * 8 + j * 2 + kk) * 64 + lane];
    }

    // S = Q K^T (log2-domain)
    f32x4 s[4];
#pragma unroll
    for (int j = 0; j < 4; ++j) s[j] = zero;
    __builtin_amdgcn_s_setprio(1);
#pragma unroll
    for (int j = 0; j < 4; ++j)
#pragma unroll
      for (int kk = 0; kk < 2; ++kk)
        s[j] = mfma16(aq[kk], kfr[j][kk], s[j]);
    __builtin_amdgcn_s_setprio(0);

    // causal mask only on the last tile (wave-uniform branch)
    if (kt == nkt - 1) {
#pragma unroll
      for (int j = 0; j < 4; ++j) {
        int keyg = kt * 64 + j * 16 + fr;
#pragma unroll
        for (int r = 0; r < 4; ++r)
          if (keyg > qbase + fq * 4 + r) s[j][r] = -1e30f;
      }
    }

    // per-lane partial row max; cross-lane reduce only when defer triggers
    float mt[4];
#pragma unroll
    for (int r = 0; r < 4; ++r) mt[r] = s[0][r];
#pragma unroll
    for (int j = 1; j < 4; ++j)
#pragma unroll
      for (int r = 0; r < 4; ++r) mt[r] = fmaxf(mt[r], s[j][r]);

    int nd = 0;
#pragma unroll
    for (int r = 0; r < 4; ++r) nd |= (mt[r] > m_r[r] + 8.f) ? 1 : 0;
    if (__any(nd)) {
#pragma unroll
      for (int msk = 1; msk < 16; msk <<= 1)
#pragma unroll
        for (int r = 0; r < 4; ++r) mt[r] = fmaxf(mt[r], __shfl_xor(mt[r], msk));
#pragma unroll
      for (int r = 0; r < 4; ++r) {
        float mn = fmaxf(m_r[r], mt[r]);
        float alpha = __builtin_amdgcn_exp2f(m_r[r] - mn);
        m_r[r] = mn;
        l_r[r] *= alpha;
#pragma unroll
        for (int i = 0; i < 4; ++i) o[i][r] *= alpha;
      }
    }

    // P = exp2(S - m); per-lane partial l; P via per-wave LDS (swizzled)
#pragma unroll
    for (int j = 0; j < 4; ++j) {
#pragma unroll
      for (int r = 0; r < 4; ++r) {
        float e = __builtin_amdgcn_exp2f(s[j][r] - m_r[r]);
        l_r[r] += e;
        int qr = fq * 4 + r;
        int key2 = (j * 16 + fr) * 2;
        *(u16*)(Pw + qr * 128 + (key2 ^ ((qr & 7) << 4))) = f2bf(e);
      }
    }

    // O += P V
    __builtin_amdgcn_s_setprio(1);
#pragma unroll
    for (int kk = 0; kk < 2; ++kk) {
      int cbP = (kk * 64 + fq * 16) ^ ((fr & 7) << 4);
      bf16x8 pa = *(const bf16x8*)(Pw + fr * 128 + cbP);
#pragma unroll
      for (int fo = 0; fo < 4; ++fo)
        o[fo] = mfma16(pa, vfr[fo][kk], o[fo]);
    }
    __builtin_amdgcn_s_setprio(0);

    if (kt + 1 < nkt) {
#pragma unroll
      for (int j = 0; j < 4; ++j)
#pragma unroll
        for (int kk = 0; kk < 2; ++kk)
          kfr[j][kk] = knx[j][kk];
    }
  }

  // final l reduce (once) + normalize + write ctx [B,S,D] bf16
#pragma unroll
  for (int msk = 1; msk < 16; msk <<= 1)
#pragma unroll
    for (int r = 0; r < 4; ++r) l_r[r] += __shfl_xor(l_r[r], msk);

#pragma unroll
  for (int fo = 0; fo < 4; ++fo) {
    int dh = fo * 16 + fr;
#pragma unroll
    for (int r = 0; r < 4; ++r) {
      int qg = qbase + fq * 4 + r;
      ctx[((size_t)b * Sz + qg) * Dz + h * DHz + dh] = f2bf(o[fo][r] / l_r[r]);
    }
  }
}

// ---------------- launch ----------------
extern "C" void kernel_launch(void* const* d_in, const int* in_sizes, int n_in,
                              void* d_out, int out_size, void* d_ws, size_t ws_size,
                              hipStream_t stream) {
  const float* q  = (const float*)d_in[0];
  const float* k  = (const float*)d_in[1];
  const float* v  = (const float*)d_in[2];
  const float* Wq = (const float*)d_in[3];
  const float* bq = (const float*)d_in[4];
  const float* Wk = (const float*)d_in[5];
  const float* bk = (const float*)d_in[6];
  const float* Wv = (const float*)d_in[7];
  const float* bv = (const float*)d_in[8];
  const float* Wo = (const float*)d_in[9];
  const float* bo = (const float*)d_in[10];
  float* out = (float*)d_out;

  char* ws = (char*)d_ws;
  size_t off = 0;
  auto alloc = [&](size_t bytes) {
    void* p = ws + off;
    off += (bytes + 255) & ~(size_t)255;
    return p;
  };
  u16* qb  = (u16*)alloc((size_t)Mz * Dz * 2);
  u16* kb  = (u16*)alloc((size_t)Mz * Dz * 2);
  u16* vb  = (u16*)alloc((size_t)Mz * Dz * 2);
  u16* Wqt = (u16*)alloc((size_t)Dz * Dz * 2);
  u16* Wkt = (u16*)alloc((size_t)Dz * Dz * 2);
  u16* Wvt = (u16*)alloc((size_t)Dz * Dz * 2);
  u16* Wot = (u16*)alloc((size_t)Dz * Dz * 2);
  u16* Qf  = (u16*)alloc((size_t)Bz * Hz * Sz * DHz * 2);
  u16* Kf  = (u16*)alloc((size_t)Bz * Hz * Sz * DHz * 2);
  u16* Vf  = (u16*)alloc((size_t)Bz * Hz * Sz * DHz * 2);
  u16* ctx = (u16*)alloc((size_t)Mz * Dz * 2);

  int n8 = Mz * Dz / 8;
  int cblk = (n8 + 255) / 256;
  cvt3_kernel<<<dim3(cblk, 3), 256, 0, stream>>>(q, k, v, qb, kb, vb, n8);

  wtrans4_kernel<<<dim3(Dz / 32, Dz / 32, 4), 256, 0, stream>>>(
      Wq, Wk, Wv, Wo, Wqt, Wkt, Wvt, Wot);

  gemm_qkv<<<dim3(Mz / 128, Dz / 128, 3), 256, 0, stream>>>(
      qb, kb, vb, Wqt, Wkt, Wvt, bq, bk, bv, Qf, Kf, Vf);

  attn_kernel<<<dim3(NQT16, Bz * Hz), 64, 0, stream>>>(Qf, Kf, Vf, ctx);

  gemm_out_k<<<dim3(Mz / 128, Dz / 128), 256, 0, stream>>>(ctx, Wot, bo, out);
}

// Round 15
// 115.923 us; speedup vs baseline: 2.7362x; 2.7362x over previous
//
#include <hip/hip_runtime.h>
#include <hip/hip_bf16.h>
#include <stdint.h>

#define Bz 2
#define Sz 2048
#define Dz 768
#define Hz 12
#define DHz 64
#define Mz (Bz*Sz)    // 4096
#define NQT16 128     // 16-row q-tiles per (b,h)

typedef __attribute__((ext_vector_type(4))) float f32x4;
typedef __attribute__((ext_vector_type(8))) short bf16x8;
typedef unsigned short u16;
typedef __attribute__((ext_vector_type(8))) unsigned short u16x8;

__device__ __forceinline__ u16 f2bf(float f) {
  union { float f; uint32_t u; } c; c.f = f;
  uint32_t u = c.u;
  return (u16)((u + 0x7fffu + ((u >> 16) & 1u)) >> 16);
}

#define GLL16(gsrc, ldst) \
  __builtin_amdgcn_global_load_lds((const __attribute__((address_space(1))) void*)(gsrc), \
                                   (__attribute__((address_space(3))) void*)(ldst), 16, 0, 0)

__device__ __forceinline__ f32x4 mfma16(bf16x8 a, bf16x8 b, f32x4 c) {
  return __builtin_amdgcn_mfma_f32_16x16x32_bf16(a, b, c, 0, 0, 0);
}

// ---------------- pre-pass: fp32 -> bf16 (q,k,v fused in one launch) ----------------
__global__ void cvt3_kernel(const float* __restrict__ qa, const float* __restrict__ ka,
                            const float* __restrict__ va,
                            u16* __restrict__ qo, u16* __restrict__ ko, u16* __restrict__ vo,
                            int n8) {
  int i = blockIdx.x * blockDim.x + threadIdx.x;
  if (i >= n8) return;
  int z = blockIdx.y;
  const float* src = (z == 0) ? qa : (z == 1) ? ka : va;
  u16* dst = (z == 0) ? qo : (z == 1) ? ko : vo;
  const float4* s4 = (const float4*)src;
  float4 a = s4[(size_t)i * 2];
  float4 b = s4[(size_t)i * 2 + 1];
  u16x8 o;
  o[0] = f2bf(a.x); o[1] = f2bf(a.y); o[2] = f2bf(a.z); o[3] = f2bf(a.w);
  o[4] = f2bf(b.x); o[5] = f2bf(b.y); o[6] = f2bf(b.z); o[7] = f2bf(b.w);
  *(u16x8*)(dst + (size_t)i * 8) = o;
}

// ---------------- pre-pass: W [K][N] fp32 -> Wt [N][K] bf16 (4 weights fused) ----------------
__global__ void wtrans4_kernel(const float* __restrict__ W0, const float* __restrict__ W1,
                               const float* __restrict__ W2, const float* __restrict__ W3,
                               u16* __restrict__ T0, u16* __restrict__ T1,
                               u16* __restrict__ T2, u16* __restrict__ T3) {
  __shared__ float tile[32][33];
  int z = blockIdx.z;
  const float* W = (z == 0) ? W0 : (z == 1) ? W1 : (z == 2) ? W2 : W3;
  u16* Wt = (z == 0) ? T0 : (z == 1) ? T1 : (z == 2) ? T2 : T3;
  int bx = blockIdx.x * 32, by = blockIdx.y * 32;
  int tx = threadIdx.x & 31, ty = threadIdx.x >> 5;   // 256 threads: ty 0..7
#pragma unroll
  for (int i = 0; i < 32; i += 8)
    tile[ty + i][tx] = W[(size_t)(by + ty + i) * Dz + bx + tx];
  __syncthreads();
#pragma unroll
  for (int i = 0; i < 32; i += 8)
    Wt[(size_t)(bx + ty + i) * Dz + by + tx] = f2bf(tile[tx][ty + i]);
}

// ---------------- GEMM core (R10/R13, proven): 128x128, triple-buffer, 1 barrier, counted vmcnt
// mode 0: Q -> fragment layout Qf[bh][qt=s>>4][kk=dh>>5][lane][e]         (scaled by oscale)
// mode 3: K -> fragment layout Kf[bh][kt=s>>6][j=(s>>4)&3][kk=dh>>5][lane][e]
// mode 1: V -> fragment layout Vf[bh][kt=s>>6][fo=dh>>4][kk=(s>>5)&1][lane][e]
// mode 2: fp32 out [M][N] (output projection)
__device__ __forceinline__ void gemm_core(
    const u16* __restrict__ A, const u16* __restrict__ Wt,
    const float* __restrict__ bias, void* __restrict__ out, int mode, float oscale,
    u16 (*As)[128 * 32], u16 (*Bs)[128 * 32])
{
  const int tid = threadIdx.x;
  const int wid = tid >> 6, lane = tid & 63;
  const int wm = wid >> 1, wn = wid & 1;
  const int m0 = blockIdx.x * 128, n0 = blockIdx.y * 128;
  const int fq = lane >> 4, fr = lane & 15;

  int aoff[2];
#pragma unroll
  for (int c = 0; c < 2; ++c) {
    int off  = (wid * 2 + c) * 1024 + lane * 16;
    int row  = off >> 6;
    int colb = (off & 63) ^ (((row >> 1) & 3) << 4);
    aoff[c]  = row * Dz + (colb >> 1);
  }

  int raddr[4], rbaddr[4];
#pragma unroll
  for (int f = 0; f < 4; ++f) {
    int rowA = wm * 64 + f * 16 + fr;
    raddr[f]  = rowA * 64 + ((fq * 16) ^ (((rowA >> 1) & 3) << 4));
    int rowB = wn * 64 + f * 16 + fr;
    rbaddr[f] = rowB * 64 + ((fq * 16) ^ (((rowB >> 1) & 3) << 4));
  }

  f32x4 acc[4][4];
  const f32x4 zero = {0.f, 0.f, 0.f, 0.f};
#pragma unroll
  for (int i = 0; i < 4; ++i)
#pragma unroll
    for (int j = 0; j < 4; ++j) acc[i][j] = zero;

  const u16* Abase = A + (size_t)m0 * Dz;
  const u16* Bbase = Wt + (size_t)n0 * Dz;

  const int NKT = Dz / 32;   // 24
#pragma unroll
  for (int c = 0; c < 2; ++c) {
    GLL16(Abase + aoff[c], (char*)As[0] + (wid * 2 + c) * 1024);
    GLL16(Bbase + aoff[c], (char*)Bs[0] + (wid * 2 + c) * 1024);
  }
  int cur = 0;

  for (int kt = 0; kt < NKT; ++kt) {
    int nx = cur + 1; if (nx == 3) nx = 0;
    if (kt + 1 < NKT) {
      int ke = (kt + 1) * 32;
#pragma unroll
      for (int c = 0; c < 2; ++c) {
        GLL16(Abase + ke + aoff[c], (char*)As[nx] + (wid * 2 + c) * 1024);
        GLL16(Bbase + ke + aoff[c], (char*)Bs[nx] + (wid * 2 + c) * 1024);
      }
      asm volatile("s_waitcnt vmcnt(4)" ::: "memory");
    } else {
      asm volatile("s_waitcnt vmcnt(0)" ::: "memory");
    }
    __builtin_amdgcn_s_barrier();
    __builtin_amdgcn_sched_barrier(0);

    bf16x8 af[4], bf[4];
#pragma unroll
    for (int f = 0; f < 4; ++f) {
      af[f] = *(const bf16x8*)((const char*)As[cur] + raddr[f]);
      bf[f] = *(const bf16x8*)((const char*)Bs[cur] + rbaddr[f]);
    }
    __builtin_amdgcn_s_setprio(1);
#pragma unroll
    for (int i = 0; i < 4; ++i)
#pragma unroll
      for (int j = 0; j < 4; ++j)
        acc[i][j] = mfma16(af[i], bf[j], acc[i][j]);
    __builtin_amdgcn_s_setprio(0);
    cur = nx;
  }

  if (mode == 2) {
    float* O = (float*)out;
#pragma unroll
    for (int i = 0; i < 4; ++i) {
      int grow = m0 + wm * 64 + i * 16 + fq * 4;
#pragma unroll
      for (int j = 0; j < 4; ++j) {
        int gcol = n0 + wn * 64 + j * 16 + fr;
        float bv = bias[gcol];
#pragma unroll
        for (int r = 0; r < 4; ++r)
          O[(size_t)(grow + r) * Dz + gcol] = acc[i][j][r] + bv;
      }
    }
  } else {
    u16* O = (u16*)out;
#pragma unroll
    for (int i = 0; i < 4; ++i) {
      int grow = m0 + wm * 64 + i * 16 + fq * 4;
#pragma unroll
      for (int j = 0; j < 4; ++j) {
        int gcol = n0 + wn * 64 + j * 16 + fr;
        float bv = bias[gcol];
        int h = gcol >> 6, dh = gcol & 63;
#pragma unroll
        for (int r = 0; r < 4; ++r) {
          int t = grow + r;
          int b = t >> 11, s = t & 2047;
          int bh = b * Hz + h;
          u16 val = f2bf((acc[i][j][r] + bv) * oscale);
          size_t idx;
          if (mode == 0) {        // Q frags
            idx = ((((size_t)bh * 128 + (s >> 4)) * 2 + (dh >> 5)) * 64
                   + ((dh >> 3) & 3) * 16 + (s & 15)) * 8 + (dh & 7);
          } else if (mode == 3) { // K frags
            idx = (((((size_t)bh * 32 + (s >> 6)) * 4 + ((s >> 4) & 3)) * 2 + (dh >> 5)) * 64
                   + ((dh >> 3) & 3) * 16 + (s & 15)) * 8 + (dh & 7);
          } else {                // mode 1: V frags
            idx = (((((size_t)bh * 32 + (s >> 6)) * 4 + (dh >> 4)) * 2 + ((s >> 5) & 1)) * 64
                   + ((s >> 3) & 3) * 16 + (dh & 15)) * 8 + (s & 7);
          }
          O[idx] = val;
        }
      }
    }
  }
}

// Q is pre-scaled by 1/sqrt(DH) * log2(e) so attention can use raw v_exp_f32 (exp2)
#define QSCALE 0.1803368801111404f   // 0.125 * 1.4426950408889634

__global__ __launch_bounds__(256, 2) void gemm_qkv(
    const u16* __restrict__ qb, const u16* __restrict__ kb, const u16* __restrict__ vb,
    const u16* __restrict__ Wqt, const u16* __restrict__ Wkt, const u16* __restrict__ Wvt,
    const float* __restrict__ bq, const float* __restrict__ bk, const float* __restrict__ bv,
    u16* __restrict__ Qf, u16* __restrict__ Kf, u16* __restrict__ Vf)
{
  __shared__ u16 As[3][128 * 32];
  __shared__ u16 Bs[3][128 * 32];
  const u16* A; const u16* W; const float* bias; u16* out; int mode; float osc;
  if (blockIdx.z == 0)      { A = qb; W = Wqt; bias = bq; out = Qf; mode = 0; osc = QSCALE; }
  else if (blockIdx.z == 1) { A = kb; W = Wkt; bias = bk; out = Kf; mode = 3; osc = 1.f; }
  else                      { A = vb; W = Wvt; bias = bv; out = Vf; mode = 1; osc = 1.f; }
  gemm_core(A, W, bias, out, mode, osc, As, Bs);
}

__global__ __launch_bounds__(256, 2) void gemm_out_k(
    const u16* __restrict__ ctx, const u16* __restrict__ Wot,
    const float* __restrict__ bo, float* __restrict__ out)
{
  __shared__ u16 As[3][128 * 32];
  __shared__ u16 Bs[3][128 * 32];
  gemm_core(ctx, Wot, bo, (void*)out, 2, 1.f, As, Bs);
}

// ---------------- flash attention, causal: 2 INDEPENDENT WAVES per block ----------------
// grid (NQT16/2, B*H) = (64, 24), 128-thread blocks. Wave w handles q-tile
// qt = 127 - (2*bx + w): 3072 one-tile waves (~3/SIMD), adjacent tiles per block
// for L1/L2 locality, heavy-first dispatch. NO barriers, no K/V LDS: fragments
// loaded coalesced from the preformatted Qf/Kf/Vf (L2-hit). K reloaded into the
// same registers after QK (regalloc reuse, no extra buffer); V issued early.
// Only P round-trips through per-wave 2KB LDS (same-wave lgkmcnt).
__global__ __launch_bounds__(128, 2) void attn_kernel(
    const u16* __restrict__ Qf, const u16* __restrict__ Kf,
    const u16* __restrict__ Vf, u16* __restrict__ ctx)
{
  __shared__ u16 Ps[2][16 * 64];    // 4 KB: per-wave 2KB P tile
  const int tid = threadIdx.x, wid = tid >> 6, lane = tid & 63;
  const int fq = lane >> 4, fr = lane & 15;
  const int qt = (NQT16 - 1) - (blockIdx.x * 2 + wid);   // 16-row q-tile, heavy first
  const int bh = blockIdx.y;
  const int b = bh / Hz, h = bh % Hz;
  const int qbase = qt * 16;
  const int nkt = (qbase + 79) >> 6;         // k-tiles covering keys <= qbase+15

  const bf16x8* Qf8 = (const bf16x8*)Qf + (size_t)bh * 128 * 2 * 64;
  const bf16x8* Kf8 = (const bf16x8*)Kf + (size_t)bh * 32 * 8 * 64;
  const bf16x8* Vf8 = (const bf16x8*)Vf + (size_t)bh * 32 * 8 * 64;

  bf16x8 aq[2];
#pragma unroll
  for (int kk = 0; kk < 2; ++kk)
    aq[kk] = Qf8[((size_t)qt * 2 + kk) * 64 + lane];

  const f32x4 zero = {0.f, 0.f, 0.f, 0.f};
  f32x4 o[4];
#pragma unroll
  for (int i = 0; i < 4; ++i) o[i] = zero;
  float m_r[4], l_r[4];
#pragma unroll
  for (int r = 0; r < 4; ++r) { m_r[r] = -1e30f; l_r[r] = 0.f; }

  char* Pw = (char*)Ps[wid];

  // preload K fragments for tile 0
  bf16x8 kfr[4][2], vfr[4][2];
#pragma unroll
  for (int j = 0; j < 4; ++j)
#pragma unroll
    for (int kk = 0; kk < 2; ++kk)
      kfr[j][kk] = Kf8[(size_t)(j * 2 + kk) * 64 + lane];

  for (int kt = 0; kt < nkt; ++kt) {
    // issue V loads for kt (consumed after softmax — latency hidden)
#pragma unroll
    for (int fo = 0; fo < 4; ++fo)
#pragma unroll
      for (int kk = 0; kk < 2; ++kk)
        vfr[fo][kk] = Vf8[((size_t)kt * 8 + fo * 2 + kk) * 64 + lane];

    // S = Q K^T (log2-domain)
    f32x4 s[4];
#pragma unroll
    for (int j = 0; j < 4; ++j) s[j] = zero;
    __builtin_amdgcn_s_setprio(1);
#pragma unroll
    for (int j = 0; j < 4; ++j)
#pragma unroll
      for (int kk = 0; kk < 2; ++kk)
        s[j] = mfma16(aq[kk], kfr[j][kk], s[j]);
    __builtin_amdgcn_s_setprio(0);

    // reload K for kt+1 into the same registers (issued now, consumed next iter;
    // softmax+PV below hide the L2 latency; regalloc reuses kfr)
    if (kt + 1 < nkt) {
#pragma unroll
      for (int j = 0; j < 4; ++j)
#pragma unroll
        for (int kk = 0; kk < 2; ++kk)
          kfr[j][kk] = Kf8[((size_t)(kt + 1) * 8 + j * 2 + kk) * 64 + lane];
    }

    // causal mask only on the last tile (wave-uniform branch)
    if (kt == nkt - 1) {
#pragma unroll
      for (int j = 0; j < 4; ++j) {
        int keyg = kt * 64 + j * 16 + fr;
#pragma unroll
        for (int r = 0; r < 4; ++r)
          if (keyg > qbase + fq * 4 + r) s[j][r] = -1e30f;
      }
    }

    // per-lane partial row max; cross-lane reduce only when defer triggers
    float mt[4];
#pragma unroll
    for (int r = 0; r < 4; ++r) mt[r] = s[0][r];
#pragma unroll
    for (int j = 1; j < 4; ++j)
#pragma unroll
      for (int r = 0; r < 4; ++r) mt[r] = fmaxf(mt[r], s[j][r]);

    int nd = 0;
#pragma unroll
    for (int r = 0; r < 4; ++r) nd |= (mt[r] > m_r[r] + 8.f) ? 1 : 0;
    if (__any(nd)) {
#pragma unroll
      for (int msk = 1; msk < 16; msk <<= 1)
#pragma unroll
        for (int r = 0; r < 4; ++r) mt[r] = fmaxf(mt[r], __shfl_xor(mt[r], msk));
#pragma unroll
      for (int r = 0; r < 4; ++r) {
        float mn = fmaxf(m_r[r], mt[r]);
        float alpha = __builtin_amdgcn_exp2f(m_r[r] - mn);
        m_r[r] = mn;
        l_r[r] *= alpha;
#pragma unroll
        for (int i = 0; i < 4; ++i) o[i][r] *= alpha;
      }
    }

    // P = exp2(S - m); per-lane partial l; P via per-wave LDS (swizzled)
#pragma unroll
    for (int j = 0; j < 4; ++j) {
#pragma unroll
      for (int r = 0; r < 4; ++r) {
        float e = __builtin_amdgcn_exp2f(s[j][r] - m_r[r]);
        l_r[r] += e;
        int qr = fq * 4 + r;
        int key2 = (j * 16 + fr) * 2;
        *(u16*)(Pw + qr * 128 + (key2 ^ ((qr & 7) << 4))) = f2bf(e);
      }
    }

    // O += P V
    __builtin_amdgcn_s_setprio(1);
#pragma unroll
    for (int kk = 0; kk < 2; ++kk) {
      int cbP = (kk * 64 + fq * 16) ^ ((fr & 7) << 4);
      bf16x8 pa = *(const bf16x8*)(Pw + fr * 128 + cbP);
#pragma unroll
      for (int fo = 0; fo < 4; ++fo)
        o[fo] = mfma16(pa, vfr[fo][kk], o[fo]);
    }
    __builtin_amdgcn_s_setprio(0);
  }

  // final l reduce (once) + normalize + write ctx [B,S,D] bf16
#pragma unroll
  for (int msk = 1; msk < 16; msk <<= 1)
#pragma unroll
    for (int r = 0; r < 4; ++r) l_r[r] += __shfl_xor(l_r[r], msk);

#pragma unroll
  for (int fo = 0; fo < 4; ++fo) {
    int dh = fo * 16 + fr;
#pragma unroll
    for (int r = 0; r < 4; ++r) {
      int qg = qbase + fq * 4 + r;
      ctx[((size_t)b * Sz + qg) * Dz + h * DHz + dh] = f2bf(o[fo][r] / l_r[r]);
    }
  }
}

// ---------------- launch ----------------
extern "C" void kernel_launch(void* const* d_in, const int* in_sizes, int n_in,
                              void* d_out, int out_size, void* d_ws, size_t ws_size,
                              hipStream_t stream) {
  const float* q  = (const float*)d_in[0];
  const float* k  = (const float*)d_in[1];
  const float* v  = (const float*)d_in[2];
  const float* Wq = (const float*)d_in[3];
  const float* bq = (const float*)d_in[4];
  const float* Wk = (const float*)d_in[5];
  const float* bk = (const float*)d_in[6];
  const float* Wv = (const float*)d_in[7];
  const float* bv = (const float*)d_in[8];
  const float* Wo = (const float*)d_in[9];
  const float* bo = (const float*)d_in[10];
  float* out = (float*)d_out;

  char* ws = (char*)d_ws;
  size_t off = 0;
  auto alloc = [&](size_t bytes) {
    void* p = ws + off;
    off += (bytes + 255) & ~(size_t)255;
    return p;
  };
  u16* qb  = (u16*)alloc((size_t)Mz * Dz * 2);
  u16* kb  = (u16*)alloc((size_t)Mz * Dz * 2);
  u16* vb  = (u16*)alloc((size_t)Mz * Dz * 2);
  u16* Wqt = (u16*)alloc((size_t)Dz * Dz * 2);
  u16* Wkt = (u16*)alloc((size_t)Dz * Dz * 2);
  u16* Wvt = (u16*)alloc((size_t)Dz * Dz * 2);
  u16* Wot = (u16*)alloc((size_t)Dz * Dz * 2);
  u16* Qf  = (u16*)alloc((size_t)Bz * Hz * Sz * DHz * 2);
  u16* Kf  = (u16*)alloc((size_t)Bz * Hz * Sz * DHz * 2);
  u16* Vf  = (u16*)alloc((size_t)Bz * Hz * Sz * DHz * 2);
  u16* ctx = (u16*)alloc((size_t)Mz * Dz * 2);

  int n8 = Mz * Dz / 8;
  int cblk = (n8 + 255) / 256;
  cvt3_kernel<<<dim3(cblk, 3), 256, 0, stream>>>(q, k, v, qb, kb, vb, n8);

  wtrans4_kernel<<<dim3(Dz / 32, Dz / 32, 4), 256, 0, stream>>>(
      Wq, Wk, Wv, Wo, Wqt, Wkt, Wvt, Wot);

  gemm_qkv<<<dim3(Mz / 128, Dz / 128, 3), 256, 0, stream>>>(
      qb, kb, vb, Wqt, Wkt, Wvt, bq, bk, bv, Qf, Kf, Vf);

  attn_kernel<<<dim3(NQT16 / 2, Bz * Hz), 128, 0, stream>>>(Qf, Kf, Vf, ctx);

  gemm_out_k<<<dim3(Mz / 128, Dz / 128), 256, 0, stream>>>(ctx, Wot, bo, out);
}

// Round 16
// 115.905 us; speedup vs baseline: 2.7366x; 1.0002x over previous
//
#include <hip/hip_runtime.h>
#include <hip/hip_bf16.h>
#include <stdint.h>

#define Bz 2
#define Sz 2048
#define Dz 768
#define Hz 12
#define DHz 64
#define Mz (Bz*Sz)    // 4096
#define NQT16 128     // 16-row q-tiles per (b,h)

typedef __attribute__((ext_vector_type(4))) float f32x4;
typedef __attribute__((ext_vector_type(8))) short bf16x8;
typedef unsigned short u16;
typedef __attribute__((ext_vector_type(8))) unsigned short u16x8;

__device__ __forceinline__ u16 f2bf(float f) {
  union { float f; uint32_t u; } c; c.f = f;
  uint32_t u = c.u;
  return (u16)((u + 0x7fffu + ((u >> 16) & 1u)) >> 16);
}

#define GLL16(gsrc, ldst) \
  __builtin_amdgcn_global_load_lds((const __attribute__((address_space(1))) void*)(gsrc), \
                                   (__attribute__((address_space(3))) void*)(ldst), 16, 0, 0)

__device__ __forceinline__ f32x4 mfma16(bf16x8 a, bf16x8 b, f32x4 c) {
  return __builtin_amdgcn_mfma_f32_16x16x32_bf16(a, b, c, 0, 0, 0);
}

// ---------------- pre-pass: fp32 -> bf16 (q,k,v fused in one launch) ----------------
__global__ void cvt3_kernel(const float* __restrict__ qa, const float* __restrict__ ka,
                            const float* __restrict__ va,
                            u16* __restrict__ qo, u16* __restrict__ ko, u16* __restrict__ vo,
                            int n8) {
  int i = blockIdx.x * blockDim.x + threadIdx.x;
  if (i >= n8) return;
  int z = blockIdx.y;
  const float* src = (z == 0) ? qa : (z == 1) ? ka : va;
  u16* dst = (z == 0) ? qo : (z == 1) ? ko : vo;
  const float4* s4 = (const float4*)src;
  float4 a = s4[(size_t)i * 2];
  float4 b = s4[(size_t)i * 2 + 1];
  u16x8 o;
  o[0] = f2bf(a.x); o[1] = f2bf(a.y); o[2] = f2bf(a.z); o[3] = f2bf(a.w);
  o[4] = f2bf(b.x); o[5] = f2bf(b.y); o[6] = f2bf(b.z); o[7] = f2bf(b.w);
  *(u16x8*)(dst + (size_t)i * 8) = o;
}

// ---------------- pre-pass: W [K][N] fp32 -> Wt [N][K] bf16 (4 weights fused) ----------------
__global__ void wtrans4_kernel(const float* __restrict__ W0, const float* __restrict__ W1,
                               const float* __restrict__ W2, const float* __restrict__ W3,
                               u16* __restrict__ T0, u16* __restrict__ T1,
                               u16* __restrict__ T2, u16* __restrict__ T3) {
  __shared__ float tile[32][33];
  int z = blockIdx.z;
  const float* W = (z == 0) ? W0 : (z == 1) ? W1 : (z == 2) ? W2 : W3;
  u16* Wt = (z == 0) ? T0 : (z == 1) ? T1 : (z == 2) ? T2 : T3;
  int bx = blockIdx.x * 32, by = blockIdx.y * 32;
  int tx = threadIdx.x & 31, ty = threadIdx.x >> 5;   // 256 threads: ty 0..7
#pragma unroll
  for (int i = 0; i < 32; i += 8)
    tile[ty + i][tx] = W[(size_t)(by + ty + i) * Dz + bx + tx];
  __syncthreads();
#pragma unroll
  for (int i = 0; i < 32; i += 8)
    Wt[(size_t)(bx + ty + i) * Dz + by + tx] = f2bf(tile[tx][ty + i]);
}

// ---------------- GEMM core (R10/R13, proven): 128x128, triple-buffer, 1 barrier, counted vmcnt
// mode 0: Q -> fragment layout Qf[bh][qt=s>>4][kk=dh>>5][lane][e]         (scaled by oscale)
// mode 3: K -> fragment layout Kf[bh][kt=s>>6][j=(s>>4)&3][kk=dh>>5][lane][e]
// mode 1: V -> fragment layout Vf[bh][kt=s>>6][fo=dh>>4][kk=(s>>5)&1][lane][e]
// mode 2: fp32 out [M][N] (output projection)
__device__ __forceinline__ void gemm_core(
    const u16* __restrict__ A, const u16* __restrict__ Wt,
    const float* __restrict__ bias, void* __restrict__ out, int mode, float oscale,
    u16 (*As)[128 * 32], u16 (*Bs)[128 * 32])
{
  const int tid = threadIdx.x;
  const int wid = tid >> 6, lane = tid & 63;
  const int wm = wid >> 1, wn = wid & 1;
  const int m0 = blockIdx.x * 128, n0 = blockIdx.y * 128;
  const int fq = lane >> 4, fr = lane & 15;

  int aoff[2];
#pragma unroll
  for (int c = 0; c < 2; ++c) {
    int off  = (wid * 2 + c) * 1024 + lane * 16;
    int row  = off >> 6;
    int colb = (off & 63) ^ (((row >> 1) & 3) << 4);
    aoff[c]  = row * Dz + (colb >> 1);
  }

  int raddr[4], rbaddr[4];
#pragma unroll
  for (int f = 0; f < 4; ++f) {
    int rowA = wm * 64 + f * 16 + fr;
    raddr[f]  = rowA * 64 + ((fq * 16) ^ (((rowA >> 1) & 3) << 4));
    int rowB = wn * 64 + f * 16 + fr;
    rbaddr[f] = rowB * 64 + ((fq * 16) ^ (((rowB >> 1) & 3) << 4));
  }

  f32x4 acc[4][4];
  const f32x4 zero = {0.f, 0.f, 0.f, 0.f};
#pragma unroll
  for (int i = 0; i < 4; ++i)
#pragma unroll
    for (int j = 0; j < 4; ++j) acc[i][j] = zero;

  const u16* Abase = A + (size_t)m0 * Dz;
  const u16* Bbase = Wt + (size_t)n0 * Dz;

  const int NKT = Dz / 32;   // 24
#pragma unroll
  for (int c = 0; c < 2; ++c) {
    GLL16(Abase + aoff[c], (char*)As[0] + (wid * 2 + c) * 1024);
    GLL16(Bbase + aoff[c], (char*)Bs[0] + (wid * 2 + c) * 1024);
  }
  int cur = 0;

  for (int kt = 0; kt < NKT; ++kt) {
    int nx = cur + 1; if (nx == 3) nx = 0;
    if (kt + 1 < NKT) {
      int ke = (kt + 1) * 32;
#pragma unroll
      for (int c = 0; c < 2; ++c) {
        GLL16(Abase + ke + aoff[c], (char*)As[nx] + (wid * 2 + c) * 1024);
        GLL16(Bbase + ke + aoff[c], (char*)Bs[nx] + (wid * 2 + c) * 1024);
      }
      asm volatile("s_waitcnt vmcnt(4)" ::: "memory");
    } else {
      asm volatile("s_waitcnt vmcnt(0)" ::: "memory");
    }
    __builtin_amdgcn_s_barrier();
    __builtin_amdgcn_sched_barrier(0);

    bf16x8 af[4], bf[4];
#pragma unroll
    for (int f = 0; f < 4; ++f) {
      af[f] = *(const bf16x8*)((const char*)As[cur] + raddr[f]);
      bf[f] = *(const bf16x8*)((const char*)Bs[cur] + rbaddr[f]);
    }
    __builtin_amdgcn_s_setprio(1);
#pragma unroll
    for (int i = 0; i < 4; ++i)
#pragma unroll
      for (int j = 0; j < 4; ++j)
        acc[i][j] = mfma16(af[i], bf[j], acc[i][j]);
    __builtin_amdgcn_s_setprio(0);
    cur = nx;
  }

  if (mode == 2) {
    float* O = (float*)out;
#pragma unroll
    for (int i = 0; i < 4; ++i) {
      int grow = m0 + wm * 64 + i * 16 + fq * 4;
#pragma unroll
      for (int j = 0; j < 4; ++j) {
        int gcol = n0 + wn * 64 + j * 16 + fr;
        float bv = bias[gcol];
#pragma unroll
        for (int r = 0; r < 4; ++r)
          O[(size_t)(grow + r) * Dz + gcol] = acc[i][j][r] + bv;
      }
    }
  } else {
    u16* O = (u16*)out;
#pragma unroll
    for (int i = 0; i < 4; ++i) {
      int grow = m0 + wm * 64 + i * 16 + fq * 4;
#pragma unroll
      for (int j = 0; j < 4; ++j) {
        int gcol = n0 + wn * 64 + j * 16 + fr;
        float bv = bias[gcol];
        int h = gcol >> 6, dh = gcol & 63;
#pragma unroll
        for (int r = 0; r < 4; ++r) {
          int t = grow + r;
          int b = t >> 11, s = t & 2047;
          int bh = b * Hz + h;
          u16 val = f2bf((acc[i][j][r] + bv) * oscale);
          size_t idx;
          if (mode == 0) {        // Q frags
            idx = ((((size_t)bh * 128 + (s >> 4)) * 2 + (dh >> 5)) * 64
                   + ((dh >> 3) & 3) * 16 + (s & 15)) * 8 + (dh & 7);
          } else if (mode == 3) { // K frags
            idx = (((((size_t)bh * 32 + (s >> 6)) * 4 + ((s >> 4) & 3)) * 2 + (dh >> 5)) * 64
                   + ((dh >> 3) & 3) * 16 + (s & 15)) * 8 + (dh & 7);
          } else {                // mode 1: V frags
            idx = (((((size_t)bh * 32 + (s >> 6)) * 4 + (dh >> 4)) * 2 + ((s >> 5) & 1)) * 64
                   + ((s >> 3) & 3) * 16 + (dh & 15)) * 8 + (s & 7);
          }
          O[idx] = val;
        }
      }
    }
  }
}

// Q is pre-scaled by 1/sqrt(DH) * log2(e) so attention can use raw v_exp_f32 (exp2)
#define QSCALE 0.1803368801111404f   // 0.125 * 1.4426950408889634

__global__ __launch_bounds__(256, 2) void gemm_qkv(
    const u16* __restrict__ qb, const u16* __restrict__ kb, const u16* __restrict__ vb,
    const u16* __restrict__ Wqt, const u16* __restrict__ Wkt, const u16* __restrict__ Wvt,
    const float* __restrict__ bq, const float* __restrict__ bk, const float* __restrict__ bv,
    u16* __restrict__ Qf, u16* __restrict__ Kf, u16* __restrict__ Vf)
{
  __shared__ u16 As[3][128 * 32];
  __shared__ u16 Bs[3][128 * 32];
  const u16* A; const u16* W; const float* bias; u16* out; int mode; float osc;
  if (blockIdx.z == 0)      { A = qb; W = Wqt; bias = bq; out = Qf; mode = 0; osc = QSCALE; }
  else if (blockIdx.z == 1) { A = kb; W = Wkt; bias = bk; out = Kf; mode = 3; osc = 1.f; }
  else                      { A = vb; W = Wvt; bias = bv; out = Vf; mode = 1; osc = 1.f; }
  gemm_core(A, W, bias, out, mode, osc, As, Bs);
}

__global__ __launch_bounds__(256, 2) void gemm_out_k(
    const u16* __restrict__ ctx, const u16* __restrict__ Wot,
    const float* __restrict__ bo, float* __restrict__ out)
{
  __shared__ u16 As[3][128 * 32];
  __shared__ u16 Bs[3][128 * 32];
  gemm_core(ctx, Wot, bo, (void*)out, 2, 1.f, As, Bs);
}

// ---------------- flash attention, causal: 2 INDEPENDENT WAVES per block ----------------
// grid (NQT16/2, B*H) = (64, 24), 128-thread blocks. Wave w handles q-tile
// qt = 127 - (2*bx + w): 3072 one-tile waves (~3/SIMD), adjacent tiles per block
// for L1/L2 locality, heavy-first dispatch. NO barriers, no K/V LDS: fragments
// loaded coalesced from the preformatted Qf/Kf/Vf (L2-hit). K reloaded into the
// same registers after QK (regalloc reuse, no extra buffer); V issued early.
// Only P round-trips through per-wave 2KB LDS (same-wave lgkmcnt).
__global__ __launch_bounds__(128, 2) void attn_kernel(
    const u16* __restrict__ Qf, const u16* __restrict__ Kf,
    const u16* __restrict__ Vf, u16* __restrict__ ctx)
{
  __shared__ u16 Ps[2][16 * 64];    // 4 KB: per-wave 2KB P tile
  const int tid = threadIdx.x, wid = tid >> 6, lane = tid & 63;
  const int fq = lane >> 4, fr = lane & 15;
  const int qt = (NQT16 - 1) - (blockIdx.x * 2 + wid);   // 16-row q-tile, heavy first
  const int bh = blockIdx.y;
  const int b = bh / Hz, h = bh % Hz;
  const int qbase = qt * 16;
  const int nkt = (qbase + 79) >> 6;         // k-tiles covering keys <= qbase+15

  const bf16x8* Qf8 = (const bf16x8*)Qf + (size_t)bh * 128 * 2 * 64;
  const bf16x8* Kf8 = (const bf16x8*)Kf + (size_t)bh * 32 * 8 * 64;
  const bf16x8* Vf8 = (const bf16x8*)Vf + (size_t)bh * 32 * 8 * 64;

  bf16x8 aq[2];
#pragma unroll
  for (int kk = 0; kk < 2; ++kk)
    aq[kk] = Qf8[((size_t)qt * 2 + kk) * 64 + lane];

  const f32x4 zero = {0.f, 0.f, 0.f, 0.f};
  f32x4 o[4];
#pragma unroll
  for (int i = 0; i < 4; ++i) o[i] = zero;
  float m_r[4], l_r[4];
#pragma unroll
  for (int r = 0; r < 4; ++r) { m_r[r] = -1e30f; l_r[r] = 0.f; }

  char* Pw = (char*)Ps[wid];

  // preload K fragments for tile 0
  bf16x8 kfr[4][2], vfr[4][2];
#pragma unroll
  for (int j = 0; j < 4; ++j)
#pragma unroll
    for (int kk = 0; kk < 2; ++kk)
      kfr[j][kk] = Kf8[(size_t)(j * 2 + kk) * 64 + lane];

  for (int kt = 0; kt < nkt; ++kt) {
    // issue V loads for kt (consumed after softmax — latency hidden)
#pragma unroll
    for (int fo = 0; fo < 4; ++fo)
#pragma unroll
      for (int kk = 0; kk < 2; ++kk)
        vfr[fo][kk] = Vf8[((size_t)kt * 8 + fo * 2 + kk) * 64 + lane];

    // S = Q K^T (log2-domain)
    f32x4 s[4];
#pragma unroll
    for (int j = 0; j < 4; ++j) s[j] = zero;
    __builtin_amdgcn_s_setprio(1);
#pragma unroll
    for (int j = 0; j < 4; ++j)
#pragma unroll
      for (int kk = 0; kk < 2; ++kk)
        s[j] = mfma16(aq[kk], kfr[j][kk], s[j]);
    __builtin_amdgcn_s_setprio(0);

    // reload K for kt+1 into the same registers (issued now, consumed next iter;
    // softmax+PV below hide the L2 latency; regalloc reuses kfr)
    if (kt + 1 < nkt) {
#pragma unroll
      for (int j = 0; j < 4; ++j)
#pragma unroll
        for (int kk = 0; kk < 2; ++kk)
          kfr[j][kk] = Kf8[((size_t)(kt + 1) * 8 + j * 2 + kk) * 64 + lane];
    }

    // causal mask only on the last tile (wave-uniform branch)
    if (kt == nkt - 1) {
#pragma unroll
      for (int j = 0; j < 4; ++j) {
        int keyg = kt * 64 + j * 16 + fr;
#pragma unroll
        for (int r = 0; r < 4; ++r)
          if (keyg > qbase + fq * 4 + r) s[j][r] = -1e30f;
      }
    }

    // per-lane partial row max; cross-lane reduce only when defer triggers
    float mt[4];
#pragma unroll
    for (int r = 0; r < 4; ++r) mt[r] = s[0][r];
#pragma unroll
    for (int j = 1; j < 4; ++j)
#pragma unroll
      for (int r = 0; r < 4; ++r) mt[r] = fmaxf(mt[r], s[j][r]);

    int nd = 0;
#pragma unroll
    for (int r = 0; r < 4; ++r) nd |= (mt[r] > m_r[r] + 8.f) ? 1 : 0;
    if (__any(nd)) {
#pragma unroll
      for (int msk = 1; msk < 16; msk <<= 1)
#pragma unroll
        for (int r = 0; r < 4; ++r) mt[r] = fmaxf(mt[r], __shfl_xor(mt[r], msk));
#pragma unroll
      for (int r = 0; r < 4; ++r) {
        float mn = fmaxf(m_r[r], mt[r]);
        float alpha = __builtin_amdgcn_exp2f(m_r[r] - mn);
        m_r[r] = mn;
        l_r[r] *= alpha;
#pragma unroll
        for (int i = 0; i < 4; ++i) o[i][r] *= alpha;
      }
    }

    // P = exp2(S - m); per-lane partial l; P via per-wave LDS (swizzled)
#pragma unroll
    for (int j = 0; j < 4; ++j) {
#pragma unroll
      for (int r = 0; r < 4; ++r) {
        float e = __builtin_amdgcn_exp2f(s[j][r] - m_r[r]);
        l_r[r] += e;
        int qr = fq * 4 + r;
        int key2 = (j * 16 + fr) * 2;
        *(u16*)(Pw + qr * 128 + (key2 ^ ((qr & 7) << 4))) = f2bf(e);
      }
    }

    // O += P V
    __builtin_amdgcn_s_setprio(1);
#pragma unroll
    for (int kk = 0; kk < 2; ++kk) {
      int cbP = (kk * 64 + fq * 16) ^ ((fr & 7) << 4);
      bf16x8 pa = *(const bf16x8*)(Pw + fr * 128 + cbP);
#pragma unroll
      for (int fo = 0; fo < 4; ++fo)
        o[fo] = mfma16(pa, vfr[fo][kk], o[fo]);
    }
    __builtin_amdgcn_s_setprio(0);
  }

  // final l reduce (once) + normalize + write ctx [B,S,D] bf16
#pragma unroll
  for (int msk = 1; msk < 16; msk <<= 1)
#pragma unroll
    for (int r = 0; r < 4; ++r) l_r[r] += __shfl_xor(l_r[r], msk);

#pragma unroll
  for (int fo = 0; fo < 4; ++fo) {
    int dh = fo * 16 + fr;
#pragma unroll
    for (int r = 0; r < 4; ++r) {
      int qg = qbase + fq * 4 + r;
      ctx[((size_t)b * Sz + qg) * Dz + h * DHz + dh] = f2bf(o[fo][r] / l_r[r]);
    }
  }
}

// ---------------- launch ----------------
extern "C" void kernel_launch(void* const* d_in, const int* in_sizes, int n_in,
                              void* d_out, int out_size, void* d_ws, size_t ws_size,
                              hipStream_t stream) {
  const float* q  = (const float*)d_in[0];
  const float* k  = (const float*)d_in[1];
  const float* v  = (const float*)d_in[2];
  const float* Wq = (const float*)d_in[3];
  const float* bq = (const float*)d_in[4];
  const float* Wk = (const float*)d_in[5];
  const float* bk = (const float*)d_in[6];
  const float* Wv = (const float*)d_in[7];
  const float* bv = (const float*)d_in[8];
  const float* Wo = (const float*)d_in[9];
  const float* bo = (const float*)d_in[10];
  float* out = (float*)d_out;

  char* ws = (char*)d_ws;
  size_t off = 0;
  auto alloc = [&](size_t bytes) {
    void* p = ws + off;
    off += (bytes + 255) & ~(size_t)255;
    return p;
  };
  u16* qb  = (u16*)alloc((size_t)Mz * Dz * 2);
  u16* kb  = (u16*)alloc((size_t)Mz * Dz * 2);
  u16* vb  = (u16*)alloc((size_t)Mz * Dz * 2);
  u16* Wqt = (u16*)alloc((size_t)Dz * Dz * 2);
  u16* Wkt = (u16*)alloc((size_t)Dz * Dz * 2);
  u16* Wvt = (u16*)alloc((size_t)Dz * Dz * 2);
  u16* Wot = (u16*)alloc((size_t)Dz * Dz * 2);
  u16* Qf  = (u16*)alloc((size_t)Bz * Hz * Sz * DHz * 2);
  u16* Kf  = (u16*)alloc((size_t)Bz * Hz * Sz * DHz * 2);
  u16* Vf  = (u16*)alloc((size_t)Bz * Hz * Sz * DHz * 2);
  u16* ctx = (u16*)alloc((size_t)Mz * Dz * 2);

  int n8 = Mz * Dz / 8;
  int cblk = (n8 + 255) / 256;
  cvt3_kernel<<<dim3(cblk, 3), 256, 0, stream>>>(q, k, v, qb, kb, vb, n8);

  wtrans4_kernel<<<dim3(Dz / 32, Dz / 32, 4), 256, 0, stream>>>(
      Wq, Wk, Wv, Wo, Wqt, Wkt, Wvt, Wot);

  gemm_qkv<<<dim3(Mz / 128, Dz / 128, 3), 256, 0, stream>>>(
      qb, kb, vb, Wqt, Wkt, Wvt, bq, bk, bv, Qf, Kf, Vf);

  attn_kernel<<<dim3(NQT16 / 2, Bz * Hz), 128, 0, stream>>>(Qf, Kf, Vf, ctx);

  gemm_out_k<<<dim3(Mz / 128, Dz / 128), 256, 0, stream>>>(ctx, Wot, bo, out);
}

// Round 17
// 96.079 us; speedup vs baseline: 3.3013x; 1.2064x over previous
//
#include <hip/hip_runtime.h>
#include <hip/hip_bf16.h>
#include <stdint.h>

#define Bz 2
#define Sz 2048
#define Dz 768
#define Hz 12
#define DHz 64
#define Mz (Bz*Sz)    // 4096
#define NQT32 64      // 32-row q-tiles per (b,h)

typedef __attribute__((ext_vector_type(4))) float f32x4;
typedef __attribute__((ext_vector_type(8))) short bf16x8;
typedef unsigned short u16;
typedef __attribute__((ext_vector_type(8))) unsigned short u16x8;

__device__ __forceinline__ u16 f2bf(float f) {
  union { float f; uint32_t u; } c; c.f = f;
  uint32_t u = c.u;
  return (u16)((u + 0x7fffu + ((u >> 16) & 1u)) >> 16);
}

#define GLL16(gsrc, ldst) \
  __builtin_amdgcn_global_load_lds((const __attribute__((address_space(1))) void*)(gsrc), \
                                   (__attribute__((address_space(3))) void*)(ldst), 16, 0, 0)

__device__ __forceinline__ f32x4 mfma16(bf16x8 a, bf16x8 b, f32x4 c) {
  return __builtin_amdgcn_mfma_f32_16x16x32_bf16(a, b, c, 0, 0, 0);
}

// ---------------- pre-pass: fp32 -> bf16 (q,k,v fused in one launch) ----------------
__global__ void cvt3_kernel(const float* __restrict__ qa, const float* __restrict__ ka,
                            const float* __restrict__ va,
                            u16* __restrict__ qo, u16* __restrict__ ko, u16* __restrict__ vo,
                            int n8) {
  int i = blockIdx.x * blockDim.x + threadIdx.x;
  if (i >= n8) return;
  int z = blockIdx.y;
  const float* src = (z == 0) ? qa : (z == 1) ? ka : va;
  u16* dst = (z == 0) ? qo : (z == 1) ? ko : vo;
  const float4* s4 = (const float4*)src;
  float4 a = s4[(size_t)i * 2];
  float4 b = s4[(size_t)i * 2 + 1];
  u16x8 o;
  o[0] = f2bf(a.x); o[1] = f2bf(a.y); o[2] = f2bf(a.z); o[3] = f2bf(a.w);
  o[4] = f2bf(b.x); o[5] = f2bf(b.y); o[6] = f2bf(b.z); o[7] = f2bf(b.w);
  *(u16x8*)(dst + (size_t)i * 8) = o;
}

// ---------------- pre-pass: W [K][N] fp32 -> Wt [N][K] bf16 (4 weights fused) ----------------
__global__ void wtrans4_kernel(const float* __restrict__ W0, const float* __restrict__ W1,
                               const float* __restrict__ W2, const float* __restrict__ W3,
                               u16* __restrict__ T0, u16* __restrict__ T1,
                               u16* __restrict__ T2, u16* __restrict__ T3) {
  __shared__ float tile[32][33];
  int z = blockIdx.z;
  const float* W = (z == 0) ? W0 : (z == 1) ? W1 : (z == 2) ? W2 : W3;
  u16* Wt = (z == 0) ? T0 : (z == 1) ? T1 : (z == 2) ? T2 : T3;
  int bx = blockIdx.x * 32, by = blockIdx.y * 32;
  int tx = threadIdx.x & 31, ty = threadIdx.x >> 5;   // 256 threads: ty 0..7
#pragma unroll
  for (int i = 0; i < 32; i += 8)
    tile[ty + i][tx] = W[(size_t)(by + ty + i) * Dz + bx + tx];
  __syncthreads();
#pragma unroll
  for (int i = 0; i < 32; i += 8)
    Wt[(size_t)(bx + ty + i) * Dz + by + tx] = f2bf(tile[tx][ty + i]);
}

// ---------------- GEMM core (R10/R13, proven): 128x128, triple-buffer, 1 barrier, counted vmcnt
// mode 0: Q -> fragment layout Qf[bh][qt=s>>4][kk=dh>>5][lane][e]         (scaled by oscale)
// mode 3: K -> fragment layout Kf[bh][kt=s>>6][j=(s>>4)&3][kk=dh>>5][lane][e]
// mode 1: V -> fragment layout Vf[bh][kt=s>>6][fo=dh>>4][kk=(s>>5)&1][lane][e]
// mode 2: fp32 out [M][N] (output projection)
__device__ __forceinline__ void gemm_core(
    const u16* __restrict__ A, const u16* __restrict__ Wt,
    const float* __restrict__ bias, void* __restrict__ out, int mode, float oscale,
    u16 (*As)[128 * 32], u16 (*Bs)[128 * 32])
{
  const int tid = threadIdx.x;
  const int wid = tid >> 6, lane = tid & 63;
  const int wm = wid >> 1, wn = wid & 1;
  const int m0 = blockIdx.x * 128, n0 = blockIdx.y * 128;
  const int fq = lane >> 4, fr = lane & 15;

  int aoff[2];
#pragma unroll
  for (int c = 0; c < 2; ++c) {
    int off  = (wid * 2 + c) * 1024 + lane * 16;
    int row  = off >> 6;
    int colb = (off & 63) ^ (((row >> 1) & 3) << 4);
    aoff[c]  = row * Dz + (colb >> 1);
  }

  int raddr[4], rbaddr[4];
#pragma unroll
  for (int f = 0; f < 4; ++f) {
    int rowA = wm * 64 + f * 16 + fr;
    raddr[f]  = rowA * 64 + ((fq * 16) ^ (((rowA >> 1) & 3) << 4));
    int rowB = wn * 64 + f * 16 + fr;
    rbaddr[f] = rowB * 64 + ((fq * 16) ^ (((rowB >> 1) & 3) << 4));
  }

  f32x4 acc[4][4];
  const f32x4 zero = {0.f, 0.f, 0.f, 0.f};
#pragma unroll
  for (int i = 0; i < 4; ++i)
#pragma unroll
    for (int j = 0; j < 4; ++j) acc[i][j] = zero;

  const u16* Abase = A + (size_t)m0 * Dz;
  const u16* Bbase = Wt + (size_t)n0 * Dz;

  const int NKT = Dz / 32;   // 24
#pragma unroll
  for (int c = 0; c < 2; ++c) {
    GLL16(Abase + aoff[c], (char*)As[0] + (wid * 2 + c) * 1024);
    GLL16(Bbase + aoff[c], (char*)Bs[0] + (wid * 2 + c) * 1024);
  }
  int cur = 0;

  for (int kt = 0; kt < NKT; ++kt) {
    int nx = cur + 1; if (nx == 3) nx = 0;
    if (kt + 1 < NKT) {
      int ke = (kt + 1) * 32;
#pragma unroll
      for (int c = 0; c < 2; ++c) {
        GLL16(Abase + ke + aoff[c], (char*)As[nx] + (wid * 2 + c) * 1024);
        GLL16(Bbase + ke + aoff[c], (char*)Bs[nx] + (wid * 2 + c) * 1024);
      }
      asm volatile("s_waitcnt vmcnt(4)" ::: "memory");
    } else {
      asm volatile("s_waitcnt vmcnt(0)" ::: "memory");
    }
    __builtin_amdgcn_s_barrier();
    __builtin_amdgcn_sched_barrier(0);

    bf16x8 af[4], bf[4];
#pragma unroll
    for (int f = 0; f < 4; ++f) {
      af[f] = *(const bf16x8*)((const char*)As[cur] + raddr[f]);
      bf[f] = *(const bf16x8*)((const char*)Bs[cur] + rbaddr[f]);
    }
    __builtin_amdgcn_s_setprio(1);
#pragma unroll
    for (int i = 0; i < 4; ++i)
#pragma unroll
      for (int j = 0; j < 4; ++j)
        acc[i][j] = mfma16(af[i], bf[j], acc[i][j]);
    __builtin_amdgcn_s_setprio(0);
    cur = nx;
  }

  if (mode == 2) {
    float* O = (float*)out;
#pragma unroll
    for (int i = 0; i < 4; ++i) {
      int grow = m0 + wm * 64 + i * 16 + fq * 4;
#pragma unroll
      for (int j = 0; j < 4; ++j) {
        int gcol = n0 + wn * 64 + j * 16 + fr;
        float bv = bias[gcol];
#pragma unroll
        for (int r = 0; r < 4; ++r)
          O[(size_t)(grow + r) * Dz + gcol] = acc[i][j][r] + bv;
      }
    }
  } else {
    u16* O = (u16*)out;
#pragma unroll
    for (int i = 0; i < 4; ++i) {
      int grow = m0 + wm * 64 + i * 16 + fq * 4;
#pragma unroll
      for (int j = 0; j < 4; ++j) {
        int gcol = n0 + wn * 64 + j * 16 + fr;
        float bv = bias[gcol];
        int h = gcol >> 6, dh = gcol & 63;
#pragma unroll
        for (int r = 0; r < 4; ++r) {
          int t = grow + r;
          int b = t >> 11, s = t & 2047;
          int bh = b * Hz + h;
          u16 val = f2bf((acc[i][j][r] + bv) * oscale);
          size_t idx;
          if (mode == 0) {        // Q frags
            idx = ((((size_t)bh * 128 + (s >> 4)) * 2 + (dh >> 5)) * 64
                   + ((dh >> 3) & 3) * 16 + (s & 15)) * 8 + (dh & 7);
          } else if (mode == 3) { // K frags
            idx = (((((size_t)bh * 32 + (s >> 6)) * 4 + ((s >> 4) & 3)) * 2 + (dh >> 5)) * 64
                   + ((dh >> 3) & 3) * 16 + (s & 15)) * 8 + (dh & 7);
          } else {                // mode 1: V frags
            idx = (((((size_t)bh * 32 + (s >> 6)) * 4 + (dh >> 4)) * 2 + ((s >> 5) & 1)) * 64
                   + ((s >> 3) & 3) * 16 + (dh & 15)) * 8 + (s & 7);
          }
          O[idx] = val;
        }
      }
    }
  }
}

// Q is pre-scaled by 1/sqrt(DH) * log2(e) so attention can use raw v_exp_f32 (exp2)
#define QSCALE 0.1803368801111404f   // 0.125 * 1.4426950408889634

__global__ __launch_bounds__(256, 2) void gemm_qkv(
    const u16* __restrict__ qb, const u16* __restrict__ kb, const u16* __restrict__ vb,
    const u16* __restrict__ Wqt, const u16* __restrict__ Wkt, const u16* __restrict__ Wvt,
    const float* __restrict__ bq, const float* __restrict__ bk, const float* __restrict__ bv,
    u16* __restrict__ Qf, u16* __restrict__ Kf, u16* __restrict__ Vf)
{
  __shared__ u16 As[3][128 * 32];
  __shared__ u16 Bs[3][128 * 32];
  const u16* A; const u16* W; const float* bias; u16* out; int mode; float osc;
  if (blockIdx.z == 0)      { A = qb; W = Wqt; bias = bq; out = Qf; mode = 0; osc = QSCALE; }
  else if (blockIdx.z == 1) { A = kb; W = Wkt; bias = bk; out = Kf; mode = 3; osc = 1.f; }
  else                      { A = vb; W = Wvt; bias = bv; out = Vf; mode = 1; osc = 1.f; }
  gemm_core(A, W, bias, out, mode, osc, As, Bs);
}

__global__ __launch_bounds__(256, 2) void gemm_out_k(
    const u16* __restrict__ ctx, const u16* __restrict__ Wot,
    const float* __restrict__ bo, float* __restrict__ out)
{
  __shared__ u16 As[3][128 * 32];
  __shared__ u16 Bs[3][128 * 32];
  gemm_core(ctx, Wot, bo, (void*)out, 2, 1.f, As, Bs);
}

// ---------------- flash attention, causal: R16 wave body + R13 dispatch geometry -------------
// grid (B*H, NQT32) = (24, 64): x = bh FASTEST (critical: consecutive blocks span all
// heads at the same q-position -> per-XCD L2 holds few heads' K/V; Qf/Kf/Vf stay
// L3-resident). y = 32-row tile, qt32 = 63 - y (heavy first). Block = 128 threads,
// wave w owns rows qt32*32 + w*16; both waves scan the same kt sequence (L1 sharing).
// No barriers, no K/V LDS; lean 1-group wave body (VGPR ~80) -> 3 waves/SIMD TLP.
__global__ __launch_bounds__(128, 2) void attn_kernel(
    const u16* __restrict__ Qf, const u16* __restrict__ Kf,
    const u16* __restrict__ Vf, u16* __restrict__ ctx)
{
  __shared__ u16 Ps[2][16 * 64];    // 4 KB: per-wave 2KB P tile
  const int tid = threadIdx.x, wid = tid >> 6, lane = tid & 63;
  const int fq = lane >> 4, fr = lane & 15;
  const int bh = blockIdx.x;                       // FASTEST dim
  const int qt32 = (NQT32 - 1) - blockIdx.y;       // heavy tiles first
  const int b = bh / Hz, h = bh % Hz;
  const int qt = qt32 * 2 + wid;                   // this wave's 16-row tile
  const int qbase = qt * 16;
  const int nkt = (qbase + 79) >> 6;               // k-tiles covering keys <= qbase+15

  const bf16x8* Qf8 = (const bf16x8*)Qf + (size_t)bh * 128 * 2 * 64;
  const bf16x8* Kf8 = (const bf16x8*)Kf + (size_t)bh * 32 * 8 * 64;
  const bf16x8* Vf8 = (const bf16x8*)Vf + (size_t)bh * 32 * 8 * 64;

  bf16x8 aq[2];
#pragma unroll
  for (int kk = 0; kk < 2; ++kk)
    aq[kk] = Qf8[((size_t)qt * 2 + kk) * 64 + lane];

  const f32x4 zero = {0.f, 0.f, 0.f, 0.f};
  f32x4 o[4];
#pragma unroll
  for (int i = 0; i < 4; ++i) o[i] = zero;
  float m_r[4], l_r[4];
#pragma unroll
  for (int r = 0; r < 4; ++r) { m_r[r] = -1e30f; l_r[r] = 0.f; }

  char* Pw = (char*)Ps[wid];

  // preload K fragments for tile 0
  bf16x8 kfr[4][2], vfr[4][2];
#pragma unroll
  for (int j = 0; j < 4; ++j)
#pragma unroll
    for (int kk = 0; kk < 2; ++kk)
      kfr[j][kk] = Kf8[(size_t)(j * 2 + kk) * 64 + lane];

  for (int kt = 0; kt < nkt; ++kt) {
    // issue V loads for kt (consumed after softmax — latency hidden)
#pragma unroll
    for (int fo = 0; fo < 4; ++fo)
#pragma unroll
      for (int kk = 0; kk < 2; ++kk)
        vfr[fo][kk] = Vf8[((size_t)kt * 8 + fo * 2 + kk) * 64 + lane];

    // S = Q K^T (log2-domain)
    f32x4 s[4];
#pragma unroll
    for (int j = 0; j < 4; ++j) s[j] = zero;
    __builtin_amdgcn_s_setprio(1);
#pragma unroll
    for (int j = 0; j < 4; ++j)
#pragma unroll
      for (int kk = 0; kk < 2; ++kk)
        s[j] = mfma16(aq[kk], kfr[j][kk], s[j]);
    __builtin_amdgcn_s_setprio(0);

    // reload K for kt+1 into the same registers (softmax+PV hide the L2 latency)
    if (kt + 1 < nkt) {
#pragma unroll
      for (int j = 0; j < 4; ++j)
#pragma unroll
        for (int kk = 0; kk < 2; ++kk)
          kfr[j][kk] = Kf8[((size_t)(kt + 1) * 8 + j * 2 + kk) * 64 + lane];
    }

    // causal mask only on the last tile (wave-uniform branch)
    if (kt == nkt - 1) {
#pragma unroll
      for (int j = 0; j < 4; ++j) {
        int keyg = kt * 64 + j * 16 + fr;
#pragma unroll
        for (int r = 0; r < 4; ++r)
          if (keyg > qbase + fq * 4 + r) s[j][r] = -1e30f;
      }
    }

    // per-lane partial row max; cross-lane reduce only when defer triggers
    float mt[4];
#pragma unroll
    for (int r = 0; r < 4; ++r) mt[r] = s[0][r];
#pragma unroll
    for (int j = 1; j < 4; ++j)
#pragma unroll
      for (int r = 0; r < 4; ++r) mt[r] = fmaxf(mt[r], s[j][r]);

    int nd = 0;
#pragma unroll
    for (int r = 0; r < 4; ++r) nd |= (mt[r] > m_r[r] + 8.f) ? 1 : 0;
    if (__any(nd)) {
#pragma unroll
      for (int msk = 1; msk < 16; msk <<= 1)
#pragma unroll
        for (int r = 0; r < 4; ++r) mt[r] = fmaxf(mt[r], __shfl_xor(mt[r], msk));
#pragma unroll
      for (int r = 0; r < 4; ++r) {
        float mn = fmaxf(m_r[r], mt[r]);
        float alpha = __builtin_amdgcn_exp2f(m_r[r] - mn);
        m_r[r] = mn;
        l_r[r] *= alpha;
#pragma unroll
        for (int i = 0; i < 4; ++i) o[i][r] *= alpha;
      }
    }

    // P = exp2(S - m); per-lane partial l; P via per-wave LDS (swizzled)
#pragma unroll
    for (int j = 0; j < 4; ++j) {
#pragma unroll
      for (int r = 0; r < 4; ++r) {
        float e = __builtin_amdgcn_exp2f(s[j][r] - m_r[r]);
        l_r[r] += e;
        int qr = fq * 4 + r;
        int key2 = (j * 16 + fr) * 2;
        *(u16*)(Pw + qr * 128 + (key2 ^ ((qr & 7) << 4))) = f2bf(e);
      }
    }

    // O += P V
    __builtin_amdgcn_s_setprio(1);
#pragma unroll
    for (int kk = 0; kk < 2; ++kk) {
      int cbP = (kk * 64 + fq * 16) ^ ((fr & 7) << 4);
      bf16x8 pa = *(const bf16x8*)(Pw + fr * 128 + cbP);
#pragma unroll
      for (int fo = 0; fo < 4; ++fo)
        o[fo] = mfma16(pa, vfr[fo][kk], o[fo]);
    }
    __builtin_amdgcn_s_setprio(0);
  }

  // final l reduce (once) + normalize + write ctx [B,S,D] bf16
#pragma unroll
  for (int msk = 1; msk < 16; msk <<= 1)
#pragma unroll
    for (int r = 0; r < 4; ++r) l_r[r] += __shfl_xor(l_r[r], msk);

#pragma unroll
  for (int fo = 0; fo < 4; ++fo) {
    int dh = fo * 16 + fr;
#pragma unroll
    for (int r = 0; r < 4; ++r) {
      int qg = qbase + fq * 4 + r;
      ctx[((size_t)b * Sz + qg) * Dz + h * DHz + dh] = f2bf(o[fo][r] / l_r[r]);
    }
  }
}

// ---------------- launch ----------------
extern "C" void kernel_launch(void* const* d_in, const int* in_sizes, int n_in,
                              void* d_out, int out_size, void* d_ws, size_t ws_size,
                              hipStream_t stream) {
  const float* q  = (const float*)d_in[0];
  const float* k  = (const float*)d_in[1];
  const float* v  = (const float*)d_in[2];
  const float* Wq = (const float*)d_in[3];
  const float* bq = (const float*)d_in[4];
  const float* Wk = (const float*)d_in[5];
  const float* bk = (const float*)d_in[6];
  const float* Wv = (const float*)d_in[7];
  const float* bv = (const float*)d_in[8];
  const float* Wo = (const float*)d_in[9];
  const float* bo = (const float*)d_in[10];
  float* out = (float*)d_out;

  char* ws = (char*)d_ws;
  size_t off = 0;
  auto alloc = [&](size_t bytes) {
    void* p = ws + off;
    off += (bytes + 255) & ~(size_t)255;
    return p;
  };
  u16* qb  = (u16*)alloc((size_t)Mz * Dz * 2);
  u16* kb  = (u16*)alloc((size_t)Mz * Dz * 2);
  u16* vb  = (u16*)alloc((size_t)Mz * Dz * 2);
  u16* Wqt = (u16*)alloc((size_t)Dz * Dz * 2);
  u16* Wkt = (u16*)alloc((size_t)Dz * Dz * 2);
  u16* Wvt = (u16*)alloc((size_t)Dz * Dz * 2);
  u16* Wot = (u16*)alloc((size_t)Dz * Dz * 2);
  u16* Qf  = (u16*)alloc((size_t)Bz * Hz * Sz * DHz * 2);
  u16* Kf  = (u16*)alloc((size_t)Bz * Hz * Sz * DHz * 2);
  u16* Vf  = (u16*)alloc((size_t)Bz * Hz * Sz * DHz * 2);
  u16* ctx = (u16*)alloc((size_t)Mz * Dz * 2);

  int n8 = Mz * Dz / 8;
  int cblk = (n8 + 255) / 256;
  cvt3_kernel<<<dim3(cblk, 3), 256, 0, stream>>>(q, k, v, qb, kb, vb, n8);

  wtrans4_kernel<<<dim3(Dz / 32, Dz / 32, 4), 256, 0, stream>>>(
      Wq, Wk, Wv, Wo, Wqt, Wkt, Wvt, Wot);

  gemm_qkv<<<dim3(Mz / 128, Dz / 128, 3), 256, 0, stream>>>(
      qb, kb, vb, Wqt, Wkt, Wvt, bq, bk, bv, Qf, Kf, Vf);

  attn_kernel<<<dim3(Bz * Hz, NQT32), 128, 0, stream>>>(Qf, Kf, Vf, ctx);

  gemm_out_k<<<dim3(Mz / 128, Dz / 128), 256, 0, stream>>>(ctx, Wot, bo, out);
}

// Round 18
// 93.183 us; speedup vs baseline: 3.4039x; 1.0311x over previous
//
#include <hip/hip_runtime.h>
#include <hip/hip_bf16.h>
#include <stdint.h>

#define Bz 2
#define Sz 2048
#define Dz 768
#define Hz 12
#define DHz 64
#define Mz (Bz*Sz)    // 4096
#define NQT16 128     // 16-row q-tiles per (b,h)

typedef __attribute__((ext_vector_type(4))) float f32x4;
typedef __attribute__((ext_vector_type(8))) short bf16x8;
typedef unsigned short u16;
typedef __attribute__((ext_vector_type(8))) unsigned short u16x8;

__device__ __forceinline__ u16 f2bf(float f) {
  union { float f; uint32_t u; } c; c.f = f;
  uint32_t u = c.u;
  return (u16)((u + 0x7fffu + ((u >> 16) & 1u)) >> 16);
}

#define GLL16(gsrc, ldst) \
  __builtin_amdgcn_global_load_lds((const __attribute__((address_space(1))) void*)(gsrc), \
                                   (__attribute__((address_space(3))) void*)(ldst), 16, 0, 0)

__device__ __forceinline__ f32x4 mfma16(bf16x8 a, bf16x8 b, f32x4 c) {
  return __builtin_amdgcn_mfma_f32_16x16x32_bf16(a, b, c, 0, 0, 0);
}

// ---------------- pre-pass: fp32 -> bf16 (q,k,v fused in one launch) ----------------
__global__ void cvt3_kernel(const float* __restrict__ qa, const float* __restrict__ ka,
                            const float* __restrict__ va,
                            u16* __restrict__ qo, u16* __restrict__ ko, u16* __restrict__ vo,
                            int n8) {
  int i = blockIdx.x * blockDim.x + threadIdx.x;
  if (i >= n8) return;
  int z = blockIdx.y;
  const float* src = (z == 0) ? qa : (z == 1) ? ka : va;
  u16* dst = (z == 0) ? qo : (z == 1) ? ko : vo;
  const float4* s4 = (const float4*)src;
  float4 a = s4[(size_t)i * 2];
  float4 b = s4[(size_t)i * 2 + 1];
  u16x8 o;
  o[0] = f2bf(a.x); o[1] = f2bf(a.y); o[2] = f2bf(a.z); o[3] = f2bf(a.w);
  o[4] = f2bf(b.x); o[5] = f2bf(b.y); o[6] = f2bf(b.z); o[7] = f2bf(b.w);
  *(u16x8*)(dst + (size_t)i * 8) = o;
}

// ---------------- pre-pass: W [K][N] fp32 -> Wt [N][K] bf16 (4 weights fused) ----------------
__global__ void wtrans4_kernel(const float* __restrict__ W0, const float* __restrict__ W1,
                               const float* __restrict__ W2, const float* __restrict__ W3,
                               u16* __restrict__ T0, u16* __restrict__ T1,
                               u16* __restrict__ T2, u16* __restrict__ T3) {
  __shared__ float tile[32][33];
  int z = blockIdx.z;
  const float* W = (z == 0) ? W0 : (z == 1) ? W1 : (z == 2) ? W2 : W3;
  u16* Wt = (z == 0) ? T0 : (z == 1) ? T1 : (z == 2) ? T2 : T3;
  int bx = blockIdx.x * 32, by = blockIdx.y * 32;
  int tx = threadIdx.x & 31, ty = threadIdx.x >> 5;   // 256 threads: ty 0..7
#pragma unroll
  for (int i = 0; i < 32; i += 8)
    tile[ty + i][tx] = W[(size_t)(by + ty + i) * Dz + bx + tx];
  __syncthreads();
#pragma unroll
  for (int i = 0; i < 32; i += 8)
    Wt[(size_t)(bx + ty + i) * Dz + by + tx] = f2bf(tile[tx][ty + i]);
}

// ---------------- GEMM core (R10/R13, proven): 128x128, triple-buffer, 1 barrier, counted vmcnt
// mode 0: Q -> fragment layout Qf[bh][qt=s>>4][kk=dh>>5][lane][e]         (scaled by oscale)
// mode 3: K -> fragment layout Kf[bh][kt=s>>6][j=(s>>4)&3][kk=dh>>5][lane][e]
// mode 1: V -> fragment layout Vf[bh][kt=s>>6][fo=dh>>4][kk=(s>>5)&1][lane][e]
// mode 2: fp32 out [M][N] (output projection)
__device__ __forceinline__ void gemm_core(
    const u16* __restrict__ A, const u16* __restrict__ Wt,
    const float* __restrict__ bias, void* __restrict__ out, int mode, float oscale,
    u16 (*As)[128 * 32], u16 (*Bs)[128 * 32])
{
  const int tid = threadIdx.x;
  const int wid = tid >> 6, lane = tid & 63;
  const int wm = wid >> 1, wn = wid & 1;
  const int m0 = blockIdx.x * 128, n0 = blockIdx.y * 128;
  const int fq = lane >> 4, fr = lane & 15;

  int aoff[2];
#pragma unroll
  for (int c = 0; c < 2; ++c) {
    int off  = (wid * 2 + c) * 1024 + lane * 16;
    int row  = off >> 6;
    int colb = (off & 63) ^ (((row >> 1) & 3) << 4);
    aoff[c]  = row * Dz + (colb >> 1);
  }

  int raddr[4], rbaddr[4];
#pragma unroll
  for (int f = 0; f < 4; ++f) {
    int rowA = wm * 64 + f * 16 + fr;
    raddr[f]  = rowA * 64 + ((fq * 16) ^ (((rowA >> 1) & 3) << 4));
    int rowB = wn * 64 + f * 16 + fr;
    rbaddr[f] = rowB * 64 + ((fq * 16) ^ (((rowB >> 1) & 3) << 4));
  }

  f32x4 acc[4][4];
  const f32x4 zero = {0.f, 0.f, 0.f, 0.f};
#pragma unroll
  for (int i = 0; i < 4; ++i)
#pragma unroll
    for (int j = 0; j < 4; ++j) acc[i][j] = zero;

  const u16* Abase = A + (size_t)m0 * Dz;
  const u16* Bbase = Wt + (size_t)n0 * Dz;

  const int NKT = Dz / 32;   // 24
#pragma unroll
  for (int c = 0; c < 2; ++c) {
    GLL16(Abase + aoff[c], (char*)As[0] + (wid * 2 + c) * 1024);
    GLL16(Bbase + aoff[c], (char*)Bs[0] + (wid * 2 + c) * 1024);
  }
  int cur = 0;

  for (int kt = 0; kt < NKT; ++kt) {
    int nx = cur + 1; if (nx == 3) nx = 0;
    if (kt + 1 < NKT) {
      int ke = (kt + 1) * 32;
#pragma unroll
      for (int c = 0; c < 2; ++c) {
        GLL16(Abase + ke + aoff[c], (char*)As[nx] + (wid * 2 + c) * 1024);
        GLL16(Bbase + ke + aoff[c], (char*)Bs[nx] + (wid * 2 + c) * 1024);
      }
      asm volatile("s_waitcnt vmcnt(4)" ::: "memory");
    } else {
      asm volatile("s_waitcnt vmcnt(0)" ::: "memory");
    }
    __builtin_amdgcn_s_barrier();
    __builtin_amdgcn_sched_barrier(0);

    bf16x8 af[4], bf[4];
#pragma unroll
    for (int f = 0; f < 4; ++f) {
      af[f] = *(const bf16x8*)((const char*)As[cur] + raddr[f]);
      bf[f] = *(const bf16x8*)((const char*)Bs[cur] + rbaddr[f]);
    }
    __builtin_amdgcn_s_setprio(1);
#pragma unroll
    for (int i = 0; i < 4; ++i)
#pragma unroll
      for (int j = 0; j < 4; ++j)
        acc[i][j] = mfma16(af[i], bf[j], acc[i][j]);
    __builtin_amdgcn_s_setprio(0);
    cur = nx;
  }

  if (mode == 2) {
    float* O = (float*)out;
#pragma unroll
    for (int i = 0; i < 4; ++i) {
      int grow = m0 + wm * 64 + i * 16 + fq * 4;
#pragma unroll
      for (int j = 0; j < 4; ++j) {
        int gcol = n0 + wn * 64 + j * 16 + fr;
        float bv = bias[gcol];
#pragma unroll
        for (int r = 0; r < 4; ++r)
          O[(size_t)(grow + r) * Dz + gcol] = acc[i][j][r] + bv;
      }
    }
  } else {
    u16* O = (u16*)out;
#pragma unroll
    for (int i = 0; i < 4; ++i) {
      int grow = m0 + wm * 64 + i * 16 + fq * 4;
#pragma unroll
      for (int j = 0; j < 4; ++j) {
        int gcol = n0 + wn * 64 + j * 16 + fr;
        float bv = bias[gcol];
        int h = gcol >> 6, dh = gcol & 63;
#pragma unroll
        for (int r = 0; r < 4; ++r) {
          int t = grow + r;
          int b = t >> 11, s = t & 2047;
          int bh = b * Hz + h;
          u16 val = f2bf((acc[i][j][r] + bv) * oscale);
          size_t idx;
          if (mode == 0) {        // Q frags
            idx = ((((size_t)bh * 128 + (s >> 4)) * 2 + (dh >> 5)) * 64
                   + ((dh >> 3) & 3) * 16 + (s & 15)) * 8 + (dh & 7);
          } else if (mode == 3) { // K frags
            idx = (((((size_t)bh * 32 + (s >> 6)) * 4 + ((s >> 4) & 3)) * 2 + (dh >> 5)) * 64
                   + ((dh >> 3) & 3) * 16 + (s & 15)) * 8 + (dh & 7);
          } else {                // mode 1: V frags
            idx = (((((size_t)bh * 32 + (s >> 6)) * 4 + (dh >> 4)) * 2 + ((s >> 5) & 1)) * 64
                   + ((s >> 3) & 3) * 16 + (dh & 15)) * 8 + (s & 7);
          }
          O[idx] = val;
        }
      }
    }
  }
}

// Q is pre-scaled by 1/sqrt(DH) * log2(e) so attention can use raw v_exp_f32 (exp2)
#define QSCALE 0.1803368801111404f   // 0.125 * 1.4426950408889634

__global__ __launch_bounds__(256, 2) void gemm_qkv(
    const u16* __restrict__ qb, const u16* __restrict__ kb, const u16* __restrict__ vb,
    const u16* __restrict__ Wqt, const u16* __restrict__ Wkt, const u16* __restrict__ Wvt,
    const float* __restrict__ bq, const float* __restrict__ bk, const float* __restrict__ bv,
    u16* __restrict__ Qf, u16* __restrict__ Kf, u16* __restrict__ Vf)
{
  __shared__ u16 As[3][128 * 32];
  __shared__ u16 Bs[3][128 * 32];
  const u16* A; const u16* W; const float* bias; u16* out; int mode; float osc;
  if (blockIdx.z == 0)      { A = qb; W = Wqt; bias = bq; out = Qf; mode = 0; osc = QSCALE; }
  else if (blockIdx.z == 1) { A = kb; W = Wkt; bias = bk; out = Kf; mode = 3; osc = 1.f; }
  else                      { A = vb; W = Wvt; bias = bv; out = Vf; mode = 1; osc = 1.f; }
  gemm_core(A, W, bias, out, mode, osc, As, Bs);
}

__global__ __launch_bounds__(256, 2) void gemm_out_k(
    const u16* __restrict__ ctx, const u16* __restrict__ Wot,
    const float* __restrict__ bo, float* __restrict__ out)
{
  __shared__ u16 As[3][128 * 32];
  __shared__ u16 Bs[3][128 * 32];
  gemm_core(ctx, Wot, bo, (void*)out, 2, 1.f, As, Bs);
}

// ---------------- flash attention, causal: SPLIT-K, 2 waves per q-tile ----------------
// grid (B*H, NQT16) = (24, 128): x = bh FASTEST (R17-proven L2 locality), y = tile,
// qt = 127 - y (heavy first). Block = one 16-row q-tile, 2 waves: wave w processes
// k-tiles w, w+2, w+4, ... with independent online-softmax state; one final
// __syncthreads, wave 1 publishes (o,m,l) via LDS, wave 0 merges exactly and writes.
// 6144 waves (6/SIMD TLP target); longest block drops 33 -> 17 sequential iters.
// No barriers in the main loop, no K/V LDS (fragments from preformatted Qf/Kf/Vf).
__global__ __launch_bounds__(128, 2) void attn_kernel(
    const u16* __restrict__ Qf, const u16* __restrict__ Kf,
    const u16* __restrict__ Vf, u16* __restrict__ ctx)
{
  __shared__ u16 Ps[2][16 * 64];     // 4 KB: per-wave P tile
  __shared__ float o1buf[64 * 16];   // 4 KB: wave-1 partial O
  __shared__ float ml1[2][16];       // wave-1 per-row m, l
  const int tid = threadIdx.x, wid = tid >> 6, lane = tid & 63;
  const int fq = lane >> 4, fr = lane & 15;
  const int bh = blockIdx.x;                       // FASTEST dim (L2 locality)
  const int qt = (NQT16 - 1) - blockIdx.y;         // heavy tiles first
  const int b = bh / Hz, h = bh % Hz;
  const int qbase = qt * 16;
  const int nkt = (qbase + 79) >> 6;               // k-tiles covering keys <= qbase+15

  const bf16x8* Qf8 = (const bf16x8*)Qf + (size_t)bh * 128 * 2 * 64;
  const bf16x8* Kf8 = (const bf16x8*)Kf + (size_t)bh * 32 * 8 * 64;
  const bf16x8* Vf8 = (const bf16x8*)Vf + (size_t)bh * 32 * 8 * 64;

  bf16x8 aq[2];
#pragma unroll
  for (int kk = 0; kk < 2; ++kk)
    aq[kk] = Qf8[((size_t)qt * 2 + kk) * 64 + lane];

  const f32x4 zero = {0.f, 0.f, 0.f, 0.f};
  f32x4 o[4];
#pragma unroll
  for (int i = 0; i < 4; ++i) o[i] = zero;
  float m_r[4], l_r[4];
#pragma unroll
  for (int r = 0; r < 4; ++r) { m_r[r] = -1e30f; l_r[r] = 0.f; }

  char* Pw = (char*)Ps[wid];

  // this wave's k-tiles: wid, wid+2, wid+4, ...
  if (wid < nkt) {
    bf16x8 kfr[4][2], vfr[4][2];
#pragma unroll
    for (int j = 0; j < 4; ++j)
#pragma unroll
      for (int kk = 0; kk < 2; ++kk)
        kfr[j][kk] = Kf8[((size_t)wid * 8 + j * 2 + kk) * 64 + lane];

    for (int kt = wid; kt < nkt; kt += 2) {
      // V for kt (consumed after softmax — latency hidden)
#pragma unroll
      for (int fo = 0; fo < 4; ++fo)
#pragma unroll
        for (int kk = 0; kk < 2; ++kk)
          vfr[fo][kk] = Vf8[((size_t)kt * 8 + fo * 2 + kk) * 64 + lane];

      // S = Q K^T (log2-domain)
      f32x4 s[4];
#pragma unroll
      for (int j = 0; j < 4; ++j) s[j] = zero;
      __builtin_amdgcn_s_setprio(1);
#pragma unroll
      for (int j = 0; j < 4; ++j)
#pragma unroll
        for (int kk = 0; kk < 2; ++kk)
          s[j] = mfma16(aq[kk], kfr[j][kk], s[j]);
      __builtin_amdgcn_s_setprio(0);

      // reload K for kt+2 (softmax+PV hide the L2 latency)
      if (kt + 2 < nkt) {
#pragma unroll
        for (int j = 0; j < 4; ++j)
#pragma unroll
          for (int kk = 0; kk < 2; ++kk)
            kfr[j][kk] = Kf8[((size_t)(kt + 2) * 8 + j * 2 + kk) * 64 + lane];
      }

      // causal mask only on the diagonal tile (wave-uniform branch)
      if (kt == nkt - 1) {
#pragma unroll
        for (int j = 0; j < 4; ++j) {
          int keyg = kt * 64 + j * 16 + fr;
#pragma unroll
          for (int r = 0; r < 4; ++r)
            if (keyg > qbase + fq * 4 + r) s[j][r] = -1e30f;
        }
      }

      // per-lane partial row max; cross-lane reduce only when defer triggers
      float mt[4];
#pragma unroll
      for (int r = 0; r < 4; ++r) mt[r] = s[0][r];
#pragma unroll
      for (int j = 1; j < 4; ++j)
#pragma unroll
        for (int r = 0; r < 4; ++r) mt[r] = fmaxf(mt[r], s[j][r]);

      int nd = 0;
#pragma unroll
      for (int r = 0; r < 4; ++r) nd |= (mt[r] > m_r[r] + 8.f) ? 1 : 0;
      if (__any(nd)) {
#pragma unroll
        for (int msk = 1; msk < 16; msk <<= 1)
#pragma unroll
          for (int r = 0; r < 4; ++r) mt[r] = fmaxf(mt[r], __shfl_xor(mt[r], msk));
#pragma unroll
        for (int r = 0; r < 4; ++r) {
          float mn = fmaxf(m_r[r], mt[r]);
          float alpha = __builtin_amdgcn_exp2f(m_r[r] - mn);
          m_r[r] = mn;
          l_r[r] *= alpha;
#pragma unroll
          for (int i = 0; i < 4; ++i) o[i][r] *= alpha;
        }
      }

      // P = exp2(S - m); per-lane partial l; P via per-wave LDS (swizzled)
#pragma unroll
      for (int j = 0; j < 4; ++j) {
#pragma unroll
        for (int r = 0; r < 4; ++r) {
          float e = __builtin_amdgcn_exp2f(s[j][r] - m_r[r]);
          l_r[r] += e;
          int qr = fq * 4 + r;
          int key2 = (j * 16 + fr) * 2;
          *(u16*)(Pw + qr * 128 + (key2 ^ ((qr & 7) << 4))) = f2bf(e);
        }
      }

      // O += P V
      __builtin_amdgcn_s_setprio(1);
#pragma unroll
      for (int kk = 0; kk < 2; ++kk) {
        int cbP = (kk * 64 + fq * 16) ^ ((fr & 7) << 4);
        bf16x8 pa = *(const bf16x8*)(Pw + fr * 128 + cbP);
#pragma unroll
        for (int fo = 0; fo < 4; ++fo)
          o[fo] = mfma16(pa, vfr[fo][kk], o[fo]);
      }
      __builtin_amdgcn_s_setprio(0);
    }
  }

  // per-wave l reduce (16-lane butterfly)
#pragma unroll
  for (int msk = 1; msk < 16; msk <<= 1)
#pragma unroll
    for (int r = 0; r < 4; ++r) l_r[r] += __shfl_xor(l_r[r], msk);

  // wave 1 publishes its partial state
  if (wid == 1) {
#pragma unroll
    for (int fo = 0; fo < 4; ++fo)
#pragma unroll
      for (int r = 0; r < 4; ++r)
        o1buf[lane * 16 + fo * 4 + r] = o[fo][r];
    if (fr == 0) {
#pragma unroll
      for (int r = 0; r < 4; ++r) {
        ml1[0][fq * 4 + r] = m_r[r];
        ml1[1][fq * 4 + r] = l_r[r];
      }
    }
  }
  __syncthreads();

  // wave 0 merges and writes ctx [B,S,D] bf16
  if (wid == 0) {
    float a0[4], a1[4], li[4];
#pragma unroll
    for (int r = 0; r < 4; ++r) {
      float m1 = ml1[0][fq * 4 + r];
      float l1 = ml1[1][fq * 4 + r];
      float mm = fmaxf(m_r[r], m1);
      a0[r] = __builtin_amdgcn_exp2f(m_r[r] - mm);
      a1[r] = __builtin_amdgcn_exp2f(m1 - mm);
      li[r] = 1.0f / (l_r[r] * a0[r] + l1 * a1[r]);
    }
#pragma unroll
    for (int fo = 0; fo < 4; ++fo) {
      int dh = fo * 16 + fr;
#pragma unroll
      for (int r = 0; r < 4; ++r) {
        float o1 = o1buf[lane * 16 + fo * 4 + r];
        float val = (o[fo][r] * a0[r] + o1 * a1[r]) * li[r];
        int qg = qbase + fq * 4 + r;
        ctx[((size_t)b * Sz + qg) * Dz + h * DHz + dh] = f2bf(val);
      }
    }
  }
}

// ---------------- launch ----------------
extern "C" void kernel_launch(void* const* d_in, const int* in_sizes, int n_in,
                              void* d_out, int out_size, void* d_ws, size_t ws_size,
                              hipStream_t stream) {
  const float* q  = (const float*)d_in[0];
  const float* k  = (const float*)d_in[1];
  const float* v  = (const float*)d_in[2];
  const float* Wq = (const float*)d_in[3];
  const float* bq = (const float*)d_in[4];
  const float* Wk = (const float*)d_in[5];
  const float* bk = (const float*)d_in[6];
  const float* Wv = (const float*)d_in[7];
  const float* bv = (const float*)d_in[8];
  const float* Wo = (const float*)d_in[9];
  const float* bo = (const float*)d_in[10];
  float* out = (float*)d_out;

  char* ws = (char*)d_ws;
  size_t off = 0;
  auto alloc = [&](size_t bytes) {
    void* p = ws + off;
    off += (bytes + 255) & ~(size_t)255;
    return p;
  };
  u16* qb  = (u16*)alloc((size_t)Mz * Dz * 2);
  u16* kb  = (u16*)alloc((size_t)Mz * Dz * 2);
  u16* vb  = (u16*)alloc((size_t)Mz * Dz * 2);
  u16* Wqt = (u16*)alloc((size_t)Dz * Dz * 2);
  u16* Wkt = (u16*)alloc((size_t)Dz * Dz * 2);
  u16* Wvt = (u16*)alloc((size_t)Dz * Dz * 2);
  u16* Wot = (u16*)alloc((size_t)Dz * Dz * 2);
  u16* Qf  = (u16*)alloc((size_t)Bz * Hz * Sz * DHz * 2);
  u16* Kf  = (u16*)alloc((size_t)Bz * Hz * Sz * DHz * 2);
  u16* Vf  = (u16*)alloc((size_t)Bz * Hz * Sz * DHz * 2);
  u16* ctx = (u16*)alloc((size_t)Mz * Dz * 2);

  int n8 = Mz * Dz / 8;
  int cblk = (n8 + 255) / 256;
  cvt3_kernel<<<dim3(cblk, 3), 256, 0, stream>>>(q, k, v, qb, kb, vb, n8);

  wtrans4_kernel<<<dim3(Dz / 32, Dz / 32, 4), 256, 0, stream>>>(
      Wq, Wk, Wv, Wo, Wqt, Wkt, Wvt, Wot);

  gemm_qkv<<<dim3(Mz / 128, Dz / 128, 3), 256, 0, stream>>>(
      qb, kb, vb, Wqt, Wkt, Wvt, bq, bk, bv, Qf, Kf, Vf);

  attn_kernel<<<dim3(Bz * Hz, NQT16), 128, 0, stream>>>(Qf, Kf, Vf, ctx);

  gemm_out_k<<<dim3(Mz / 128, Dz / 128), 256, 0, stream>>>(ctx, Wot, bo, out);
}

// Round 19
// 88.612 us; speedup vs baseline: 3.5795x; 1.0516x over previous
//
#include <hip/hip_runtime.h>
#include <hip/hip_bf16.h>
#include <stdint.h>

#define Bz 2
#define Sz 2048
#define Dz 768
#define Hz 12
#define DHz 64
#define Mz (Bz*Sz)    // 4096
#define NQT16 128     // 16-row q-tiles per (b,h)

typedef __attribute__((ext_vector_type(4))) float f32x4;
typedef __attribute__((ext_vector_type(8))) short bf16x8;
typedef unsigned short u16;
typedef __attribute__((ext_vector_type(8))) unsigned short u16x8;

__device__ __forceinline__ u16 f2bf(float f) {
  union { float f; uint32_t u; } c; c.f = f;
  uint32_t u = c.u;
  return (u16)((u + 0x7fffu + ((u >> 16) & 1u)) >> 16);
}

#define GLL16(gsrc, ldst) \
  __builtin_amdgcn_global_load_lds((const __attribute__((address_space(1))) void*)(gsrc), \
                                   (__attribute__((address_space(3))) void*)(ldst), 16, 0, 0)

__device__ __forceinline__ f32x4 mfma16(bf16x8 a, bf16x8 b, f32x4 c) {
  return __builtin_amdgcn_mfma_f32_16x16x32_bf16(a, b, c, 0, 0, 0);
}

// ---------------- fused pre-pass: cvt (q,k,v fp32->bf16) + 4x weight transpose ----------------
// blocks [0, 4608): cvt; blocks [4608, 6912): wtrans (32x32 tiles).
#define CVTB 1536   // Mz*Dz/8/256 per input
__global__ __launch_bounds__(256) void prep_kernel(
    const float* __restrict__ qa, const float* __restrict__ ka, const float* __restrict__ va,
    u16* __restrict__ qo, u16* __restrict__ ko, u16* __restrict__ vo,
    const float* __restrict__ W0, const float* __restrict__ W1,
    const float* __restrict__ W2, const float* __restrict__ W3,
    u16* __restrict__ T0, u16* __restrict__ T1,
    u16* __restrict__ T2, u16* __restrict__ T3)
{
  __shared__ float tile[32][33];
  int bid = blockIdx.x;
  if (bid < 3 * CVTB) {
    int z = bid / CVTB;
    int i = (bid % CVTB) * 256 + threadIdx.x;   // exact: CVTB*256 == Mz*Dz/8
    const float* src = (z == 0) ? qa : (z == 1) ? ka : va;
    u16* dst = (z == 0) ? qo : (z == 1) ? ko : vo;
    const float4* s4 = (const float4*)src;
    float4 a = s4[(size_t)i * 2];
    float4 b = s4[(size_t)i * 2 + 1];
    u16x8 o;
    o[0] = f2bf(a.x); o[1] = f2bf(a.y); o[2] = f2bf(a.z); o[3] = f2bf(a.w);
    o[4] = f2bf(b.x); o[5] = f2bf(b.y); o[6] = f2bf(b.z); o[7] = f2bf(b.w);
    *(u16x8*)(dst + (size_t)i * 8) = o;
  } else {
    int w = bid - 3 * CVTB;
    int z = w / 576;                 // 576 = (Dz/32)^2
    int rem = w - z * 576;
    int by = rem / 24, bxi = rem - by * 24;   // 24 = Dz/32
    const float* W = (z == 0) ? W0 : (z == 1) ? W1 : (z == 2) ? W2 : W3;
    u16* Wt = (z == 0) ? T0 : (z == 1) ? T1 : (z == 2) ? T2 : T3;
    int bx = bxi * 32, byy = by * 32;
    int tx = threadIdx.x & 31, ty = threadIdx.x >> 5;
#pragma unroll
    for (int i = 0; i < 32; i += 8)
      tile[ty + i][tx] = W[(size_t)(byy + ty + i) * Dz + bx + tx];
    __syncthreads();
#pragma unroll
    for (int i = 0; i < 32; i += 8)
      Wt[(size_t)(bx + ty + i) * Dz + byy + tx] = f2bf(tile[tx][ty + i]);
  }
}

// ---------------- GEMM core (R10/R13, proven): 128x128, triple-buffer, 1 barrier, counted vmcnt
// mode 0: Q -> fragment layout Qf[bh][qt=s>>4][kk=dh>>5][lane][e]         (scaled by oscale)
// mode 3: K -> fragment layout Kf[bh][kt=s>>6][j=(s>>4)&3][kk=dh>>5][lane][e]
// mode 1: V -> fragment layout Vf[bh][kt=s>>6][fo=dh>>4][kk=(s>>5)&1][lane][e]
__device__ __forceinline__ void gemm_core(
    const u16* __restrict__ A, const u16* __restrict__ Wt,
    const float* __restrict__ bias, void* __restrict__ out, int mode, float oscale,
    u16 (*As)[128 * 32], u16 (*Bs)[128 * 32])
{
  const int tid = threadIdx.x;
  const int wid = tid >> 6, lane = tid & 63;
  const int wm = wid >> 1, wn = wid & 1;
  const int m0 = blockIdx.x * 128, n0 = blockIdx.y * 128;
  const int fq = lane >> 4, fr = lane & 15;

  int aoff[2];
#pragma unroll
  for (int c = 0; c < 2; ++c) {
    int off  = (wid * 2 + c) * 1024 + lane * 16;
    int row  = off >> 6;
    int colb = (off & 63) ^ (((row >> 1) & 3) << 4);
    aoff[c]  = row * Dz + (colb >> 1);
  }

  int raddr[4], rbaddr[4];
#pragma unroll
  for (int f = 0; f < 4; ++f) {
    int rowA = wm * 64 + f * 16 + fr;
    raddr[f]  = rowA * 64 + ((fq * 16) ^ (((rowA >> 1) & 3) << 4));
    int rowB = wn * 64 + f * 16 + fr;
    rbaddr[f] = rowB * 64 + ((fq * 16) ^ (((rowB >> 1) & 3) << 4));
  }

  f32x4 acc[4][4];
  const f32x4 zero = {0.f, 0.f, 0.f, 0.f};
#pragma unroll
  for (int i = 0; i < 4; ++i)
#pragma unroll
    for (int j = 0; j < 4; ++j) acc[i][j] = zero;

  const u16* Abase = A + (size_t)m0 * Dz;
  const u16* Bbase = Wt + (size_t)n0 * Dz;

  const int NKT = Dz / 32;   // 24
#pragma unroll
  for (int c = 0; c < 2; ++c) {
    GLL16(Abase + aoff[c], (char*)As[0] + (wid * 2 + c) * 1024);
    GLL16(Bbase + aoff[c], (char*)Bs[0] + (wid * 2 + c) * 1024);
  }
  int cur = 0;

  for (int kt = 0; kt < NKT; ++kt) {
    int nx = cur + 1; if (nx == 3) nx = 0;
    if (kt + 1 < NKT) {
      int ke = (kt + 1) * 32;
#pragma unroll
      for (int c = 0; c < 2; ++c) {
        GLL16(Abase + ke + aoff[c], (char*)As[nx] + (wid * 2 + c) * 1024);
        GLL16(Bbase + ke + aoff[c], (char*)Bs[nx] + (wid * 2 + c) * 1024);
      }
      asm volatile("s_waitcnt vmcnt(4)" ::: "memory");
    } else {
      asm volatile("s_waitcnt vmcnt(0)" ::: "memory");
    }
    __builtin_amdgcn_s_barrier();
    __builtin_amdgcn_sched_barrier(0);

    bf16x8 af[4], bf[4];
#pragma unroll
    for (int f = 0; f < 4; ++f) {
      af[f] = *(const bf16x8*)((const char*)As[cur] + raddr[f]);
      bf[f] = *(const bf16x8*)((const char*)Bs[cur] + rbaddr[f]);
    }
    __builtin_amdgcn_s_setprio(1);
#pragma unroll
    for (int i = 0; i < 4; ++i)
#pragma unroll
      for (int j = 0; j < 4; ++j)
        acc[i][j] = mfma16(af[i], bf[j], acc[i][j]);
    __builtin_amdgcn_s_setprio(0);
    cur = nx;
  }

  {
    u16* O = (u16*)out;
#pragma unroll
    for (int i = 0; i < 4; ++i) {
      int grow = m0 + wm * 64 + i * 16 + fq * 4;
#pragma unroll
      for (int j = 0; j < 4; ++j) {
        int gcol = n0 + wn * 64 + j * 16 + fr;
        float bv = bias[gcol];
        int h = gcol >> 6, dh = gcol & 63;
#pragma unroll
        for (int r = 0; r < 4; ++r) {
          int t = grow + r;
          int b = t >> 11, s = t & 2047;
          int bh = b * Hz + h;
          u16 val = f2bf((acc[i][j][r] + bv) * oscale);
          size_t idx;
          if (mode == 0) {        // Q frags
            idx = ((((size_t)bh * 128 + (s >> 4)) * 2 + (dh >> 5)) * 64
                   + ((dh >> 3) & 3) * 16 + (s & 15)) * 8 + (dh & 7);
          } else if (mode == 3) { // K frags
            idx = (((((size_t)bh * 32 + (s >> 6)) * 4 + ((s >> 4) & 3)) * 2 + (dh >> 5)) * 64
                   + ((dh >> 3) & 3) * 16 + (s & 15)) * 8 + (dh & 7);
          } else {                // mode 1: V frags
            idx = (((((size_t)bh * 32 + (s >> 6)) * 4 + (dh >> 4)) * 2 + ((s >> 5) & 1)) * 64
                   + ((s >> 3) & 3) * 16 + (dh & 15)) * 8 + (s & 7);
          }
          O[idx] = val;
        }
      }
    }
  }
}

// ---------------- out-projection GEMM: 64x128 M-split tile, fp32 output ----------------
__device__ __forceinline__ void gemm_out_core64(
    const u16* __restrict__ A, const u16* __restrict__ Wt,
    const float* __restrict__ bias, float* __restrict__ O,
    u16 (*As)[64 * 32], u16 (*Bs)[128 * 32])
{
  const int tid = threadIdx.x;
  const int wid = tid >> 6, lane = tid & 63;
  const int wm = wid >> 1, wn = wid & 1;
  const int m0 = blockIdx.x * 64, n0 = blockIdx.y * 128;
  const int fq = lane >> 4, fr = lane & 15;

  int aoff;
  {
    int off  = tid * 16;
    int row  = off >> 6;
    int colb = (off & 63) ^ (((row >> 1) & 3) << 4);
    aoff = row * Dz + (colb >> 1);
  }
  int boff[2];
#pragma unroll
  for (int c = 0; c < 2; ++c) {
    int off  = tid * 16 + c * 4096;
    int row  = off >> 6;
    int colb = (off & 63) ^ (((row >> 1) & 3) << 4);
    boff[c] = row * Dz + (colb >> 1);
  }

  int raddr[2], rbaddr[4];
#pragma unroll
  for (int f = 0; f < 2; ++f) {
    int rowA = wm * 32 + f * 16 + fr;
    raddr[f] = rowA * 64 + ((fq * 16) ^ (((rowA >> 1) & 3) << 4));
  }
#pragma unroll
  for (int f = 0; f < 4; ++f) {
    int rowB = wn * 64 + f * 16 + fr;
    rbaddr[f] = rowB * 64 + ((fq * 16) ^ (((rowB >> 1) & 3) << 4));
  }

  f32x4 acc[2][4];
  const f32x4 zero = {0.f, 0.f, 0.f, 0.f};
#pragma unroll
  for (int i = 0; i < 2; ++i)
#pragma unroll
    for (int j = 0; j < 4; ++j) acc[i][j] = zero;

  const u16* Abase = A + (size_t)m0 * Dz;
  const u16* Bbase = Wt + (size_t)n0 * Dz;

  const int NKT = Dz / 32;   // 24
  GLL16(Abase + aoff, (char*)As[0] + tid * 16);
#pragma unroll
  for (int c = 0; c < 2; ++c)
    GLL16(Bbase + boff[c], (char*)Bs[0] + tid * 16 + c * 4096);
  int cur = 0;

  for (int kt = 0; kt < NKT; ++kt) {
    int nx = cur + 1; if (nx == 3) nx = 0;
    if (kt + 1 < NKT) {
      int ke = (kt + 1) * 32;
      GLL16(Abase + ke + aoff, (char*)As[nx] + tid * 16);
#pragma unroll
      for (int c = 0; c < 2; ++c)
        GLL16(Bbase + ke + boff[c], (char*)Bs[nx] + tid * 16 + c * 4096);
      asm volatile("s_waitcnt vmcnt(3)" ::: "memory");
    } else {
      asm volatile("s_waitcnt vmcnt(0)" ::: "memory");
    }
    __builtin_amdgcn_s_barrier();
    __builtin_amdgcn_sched_barrier(0);

    bf16x8 af[2], bf[4];
#pragma unroll
    for (int f = 0; f < 2; ++f)
      af[f] = *(const bf16x8*)((const char*)As[cur] + raddr[f]);
#pragma unroll
    for (int f = 0; f < 4; ++f)
      bf[f] = *(const bf16x8*)((const char*)Bs[cur] + rbaddr[f]);
    __builtin_amdgcn_s_setprio(1);
#pragma unroll
    for (int i = 0; i < 2; ++i)
#pragma unroll
      for (int j = 0; j < 4; ++j)
        acc[i][j] = mfma16(af[i], bf[j], acc[i][j]);
    __builtin_amdgcn_s_setprio(0);
    cur = nx;
  }

#pragma unroll
  for (int i = 0; i < 2; ++i) {
    int grow = m0 + wm * 32 + i * 16 + fq * 4;
#pragma unroll
    for (int j = 0; j < 4; ++j) {
      int gcol = n0 + wn * 64 + j * 16 + fr;
      float bv = bias[gcol];
#pragma unroll
      for (int r = 0; r < 4; ++r)
        O[(size_t)(grow + r) * Dz + gcol] = acc[i][j][r] + bv;
    }
  }
}

// Q is pre-scaled by 1/sqrt(DH) * log2(e) so attention can use raw v_exp_f32 (exp2)
#define QSCALE 0.1803368801111404f   // 0.125 * 1.4426950408889634

__global__ __launch_bounds__(256, 3) void gemm_qkv(
    const u16* __restrict__ qb, const u16* __restrict__ kb, const u16* __restrict__ vb,
    const u16* __restrict__ Wqt, const u16* __restrict__ Wkt, const u16* __restrict__ Wvt,
    const float* __restrict__ bq, const float* __restrict__ bk, const float* __restrict__ bv,
    u16* __restrict__ Qf, u16* __restrict__ Kf, u16* __restrict__ Vf)
{
  __shared__ u16 As[3][128 * 32];
  __shared__ u16 Bs[3][128 * 32];
  const u16* A; const u16* W; const float* bias; u16* out; int mode; float osc;
  if (blockIdx.z == 0)      { A = qb; W = Wqt; bias = bq; out = Qf; mode = 0; osc = QSCALE; }
  else if (blockIdx.z == 1) { A = kb; W = Wkt; bias = bk; out = Kf; mode = 3; osc = 1.f; }
  else                      { A = vb; W = Wvt; bias = bv; out = Vf; mode = 1; osc = 1.f; }
  gemm_core(A, W, bias, out, mode, osc, As, Bs);
}

__global__ __launch_bounds__(256, 4) void gemm_out_k(
    const u16* __restrict__ ctx, const u16* __restrict__ Wot,
    const float* __restrict__ bo, float* __restrict__ out)
{
  __shared__ u16 As[3][64 * 32];
  __shared__ u16 Bs[3][128 * 32];
  gemm_out_core64(ctx, Wot, bo, out, As, Bs);
}

// ---------------- flash attention (R18, proven): split-K, 2 waves per q-tile ----------------
__global__ __launch_bounds__(128, 2) void attn_kernel(
    const u16* __restrict__ Qf, const u16* __restrict__ Kf,
    const u16* __restrict__ Vf, u16* __restrict__ ctx)
{
  __shared__ u16 Ps[2][16 * 64];     // 4 KB: per-wave P tile
  __shared__ float o1buf[64 * 16];   // 4 KB: wave-1 partial O
  __shared__ float ml1[2][16];       // wave-1 per-row m, l
  const int tid = threadIdx.x, wid = tid >> 6, lane = tid & 63;
  const int fq = lane >> 4, fr = lane & 15;
  const int bh = blockIdx.x;                       // FASTEST dim (L2 locality)
  const int qt = (NQT16 - 1) - blockIdx.y;         // heavy tiles first
  const int b = bh / Hz, h = bh % Hz;
  const int qbase = qt * 16;
  const int nkt = (qbase + 79) >> 6;               // k-tiles covering keys <= qbase+15

  const bf16x8* Qf8 = (const bf16x8*)Qf + (size_t)bh * 128 * 2 * 64;
  const bf16x8* Kf8 = (const bf16x8*)Kf + (size_t)bh * 32 * 8 * 64;
  const bf16x8* Vf8 = (const bf16x8*)Vf + (size_t)bh * 32 * 8 * 64;

  bf16x8 aq[2];
#pragma unroll
  for (int kk = 0; kk < 2; ++kk)
    aq[kk] = Qf8[((size_t)qt * 2 + kk) * 64 + lane];

  const f32x4 zero = {0.f, 0.f, 0.f, 0.f};
  f32x4 o[4];
#pragma unroll
  for (int i = 0; i < 4; ++i) o[i] = zero;
  float m_r[4], l_r[4];
#pragma unroll
  for (int r = 0; r < 4; ++r) { m_r[r] = -1e30f; l_r[r] = 0.f; }

  char* Pw = (char*)Ps[wid];

  if (wid < nkt) {
    bf16x8 kfr[4][2], vfr[4][2];
#pragma unroll
    for (int j = 0; j < 4; ++j)
#pragma unroll
      for (int kk = 0; kk < 2; ++kk)
        kfr[j][kk] = Kf8[((size_t)wid * 8 + j * 2 + kk) * 64 + lane];

    for (int kt = wid; kt < nkt; kt += 2) {
#pragma unroll
      for (int fo = 0; fo < 4; ++fo)
#pragma unroll
        for (int kk = 0; kk < 2; ++kk)
          vfr[fo][kk] = Vf8[((size_t)kt * 8 + fo * 2 + kk) * 64 + lane];

      f32x4 s[4];
#pragma unroll
      for (int j = 0; j < 4; ++j) s[j] = zero;
      __builtin_amdgcn_s_setprio(1);
#pragma unroll
      for (int j = 0; j < 4; ++j)
#pragma unroll
        for (int kk = 0; kk < 2; ++kk)
          s[j] = mfma16(aq[kk], kfr[j][kk], s[j]);
      __builtin_amdgcn_s_setprio(0);

      if (kt + 2 < nkt) {
#pragma unroll
        for (int j = 0; j < 4; ++j)
#pragma unroll
          for (int kk = 0; kk < 2; ++kk)
            kfr[j][kk] = Kf8[((size_t)(kt + 2) * 8 + j * 2 + kk) * 64 + lane];
      }

      if (kt == nkt - 1) {
#pragma unroll
        for (int j = 0; j < 4; ++j) {
          int keyg = kt * 64 + j * 16 + fr;
#pragma unroll
          for (int r = 0; r < 4; ++r)
            if (keyg > qbase + fq * 4 + r) s[j][r] = -1e30f;
        }
      }

      float mt[4];
#pragma unroll
      for (int r = 0; r < 4; ++r) mt[r] = s[0][r];
#pragma unroll
      for (int j = 1; j < 4; ++j)
#pragma unroll
        for (int r = 0; r < 4; ++r) mt[r] = fmaxf(mt[r], s[j][r]);

      int nd = 0;
#pragma unroll
      for (int r = 0; r < 4; ++r) nd |= (mt[r] > m_r[r] + 8.f) ? 1 : 0;
      if (__any(nd)) {
#pragma unroll
        for (int msk = 1; msk < 16; msk <<= 1)
#pragma unroll
          for (int r = 0; r < 4; ++r) mt[r] = fmaxf(mt[r], __shfl_xor(mt[r], msk));
#pragma unroll
        for (int r = 0; r < 4; ++r) {
          float mn = fmaxf(m_r[r], mt[r]);
          float alpha = __builtin_amdgcn_exp2f(m_r[r] - mn);
          m_r[r] = mn;
          l_r[r] *= alpha;
#pragma unroll
          for (int i = 0; i < 4; ++i) o[i][r] *= alpha;
        }
      }

#pragma unroll
      for (int j = 0; j < 4; ++j) {
#pragma unroll
        for (int r = 0; r < 4; ++r) {
          float e = __builtin_amdgcn_exp2f(s[j][r] - m_r[r]);
          l_r[r] += e;
          int qr = fq * 4 + r;
          int key2 = (j * 16 + fr) * 2;
          *(u16*)(Pw + qr * 128 + (key2 ^ ((qr & 7) << 4))) = f2bf(e);
        }
      }

      __builtin_amdgcn_s_setprio(1);
#pragma unroll
      for (int kk = 0; kk < 2; ++kk) {
        int cbP = (kk * 64 + fq * 16) ^ ((fr & 7) << 4);
        bf16x8 pa = *(const bf16x8*)(Pw + fr * 128 + cbP);
#pragma unroll
        for (int fo = 0; fo < 4; ++fo)
          o[fo] = mfma16(pa, vfr[fo][kk], o[fo]);
      }
      __builtin_amdgcn_s_setprio(0);
    }
  }

#pragma unroll
  for (int msk = 1; msk < 16; msk <<= 1)
#pragma unroll
    for (int r = 0; r < 4; ++r) l_r[r] += __shfl_xor(l_r[r], msk);

  if (wid == 1) {
#pragma unroll
    for (int fo = 0; fo < 4; ++fo)
#pragma unroll
      for (int r = 0; r < 4; ++r)
        o1buf[lane * 16 + fo * 4 + r] = o[fo][r];
    if (fr == 0) {
#pragma unroll
      for (int r = 0; r < 4; ++r) {
        ml1[0][fq * 4 + r] = m_r[r];
        ml1[1][fq * 4 + r] = l_r[r];
      }
    }
  }
  __syncthreads();

  if (wid == 0) {
    float a0[4], a1[4], li[4];
#pragma unroll
    for (int r = 0; r < 4; ++r) {
      float m1 = ml1[0][fq * 4 + r];
      float l1 = ml1[1][fq * 4 + r];
      float mm = fmaxf(m_r[r], m1);
      a0[r] = __builtin_amdgcn_exp2f(m_r[r] - mm);
      a1[r] = __builtin_amdgcn_exp2f(m1 - mm);
      li[r] = 1.0f / (l_r[r] * a0[r] + l1 * a1[r]);
    }
#pragma unroll
    for (int fo = 0; fo < 4; ++fo) {
      int dh = fo * 16 + fr;
#pragma unroll
      for (int r = 0; r < 4; ++r) {
        float o1 = o1buf[lane * 16 + fo * 4 + r];
        float val = (o[fo][r] * a0[r] + o1 * a1[r]) * li[r];
        int qg = qbase + fq * 4 + r;
        ctx[((size_t)b * Sz + qg) * Dz + h * DHz + dh] = f2bf(val);
      }
    }
  }
}

// ---------------- launch ----------------
extern "C" void kernel_launch(void* const* d_in, const int* in_sizes, int n_in,
                              void* d_out, int out_size, void* d_ws, size_t ws_size,
                              hipStream_t stream) {
  const float* q  = (const float*)d_in[0];
  const float* k  = (const float*)d_in[1];
  const float* v  = (const float*)d_in[2];
  const float* Wq = (const float*)d_in[3];
  const float* bq = (const float*)d_in[4];
  const float* Wk = (const float*)d_in[5];
  const float* bk = (const float*)d_in[6];
  const float* Wv = (const float*)d_in[7];
  const float* bv = (const float*)d_in[8];
  const float* Wo = (const float*)d_in[9];
  const float* bo = (const float*)d_in[10];
  float* out = (float*)d_out;

  char* ws = (char*)d_ws;
  size_t off = 0;
  auto alloc = [&](size_t bytes) {
    void* p = ws + off;
    off += (bytes + 255) & ~(size_t)255;
    return p;
  };
  u16* qb  = (u16*)alloc((size_t)Mz * Dz * 2);
  u16* kb  = (u16*)alloc((size_t)Mz * Dz * 2);
  u16* vb  = (u16*)alloc((size_t)Mz * Dz * 2);
  u16* Wqt = (u16*)alloc((size_t)Dz * Dz * 2);
  u16* Wkt = (u16*)alloc((size_t)Dz * Dz * 2);
  u16* Wvt = (u16*)alloc((size_t)Dz * Dz * 2);
  u16* Wot = (u16*)alloc((size_t)Dz * Dz * 2);
  u16* Qf  = (u16*)alloc((size_t)Bz * Hz * Sz * DHz * 2);
  u16* Kf  = (u16*)alloc((size_t)Bz * Hz * Sz * DHz * 2);
  u16* Vf  = (u16*)alloc((size_t)Bz * Hz * Sz * DHz * 2);
  u16* ctx = (u16*)alloc((size_t)Mz * Dz * 2);

  prep_kernel<<<3 * CVTB + 4 * 576, 256, 0, stream>>>(
      q, k, v, qb, kb, vb, Wq, Wk, Wv, Wo, Wqt, Wkt, Wvt, Wot);

  gemm_qkv<<<dim3(Mz / 128, Dz / 128, 3), 256, 0, stream>>>(
      qb, kb, vb, Wqt, Wkt, Wvt, bq, bk, bv, Qf, Kf, Vf);

  attn_kernel<<<dim3(Bz * Hz, NQT16), 128, 0, stream>>>(Qf, Kf, Vf, ctx);

  gemm_out_k<<<dim3(Mz / 64, Dz / 128), 256, 0, stream>>>(ctx, Wot, bo, out);
}